// Round 1
// 907.495 us; speedup vs baseline: 1.3870x; 1.3870x over previous
//
#include <hip/hip_runtime.h>

#define LL 4096
#define DMODEL 1024
#define DINNER 2048
#define NHEADS 32
#define DSTATE 128
#define DINPROJ 4384
#define NPAD 4480          // 35*128 padded gemm1 N; zxb f32 row stride
#define CONVDIM 2304
#define ROWS 8192
#define CL 1024            // rows per L-chunk
#define CR 1152            // 9*128 rows computed by gemm1 per chunk (CL + 3 halo)
#define Q 64               // scan sub-chunk
#define NC 16              // sub-chunks per scan launch (CL/Q)

typedef __attribute__((ext_vector_type(8))) __bf16 bf16x8;
typedef __attribute__((ext_vector_type(4))) float f32x4;

__device__ __forceinline__ float bf2f(ushort u){ union{uint i;float f;} v; v.i=(uint)u<<16; return v.f; }
__device__ __forceinline__ ushort f2bf(float f){ union{float f;uint i;} v; v.f=f; uint r=v.i+0x7fffu+((v.i>>16)&1u); return (ushort)(r>>16); }

// ---- f32 -> bf16, 8 elems/thread ----
__global__ __launch_bounds__(256) void cvt_k(const float4* __restrict__ src, uint4* __restrict__ dst){
  long t = (long)blockIdx.x*256 + threadIdx.x;
  float4 a = src[t*2], b = src[t*2+1];
  ushort u[8] = { f2bf(a.x),f2bf(a.y),f2bf(a.z),f2bf(a.w),
                  f2bf(b.x),f2bf(b.y),f2bf(b.z),f2bf(b.w) };
  dst[t] = *(uint4*)u;
}

// ---- in_proj_w f32 (4384x1024) -> padded bf16 (4480x1024) ----
__global__ __launch_bounds__(256) void padw_cvt(const float4* __restrict__ W, ushort4* __restrict__ Wp){
  int row = blockIdx.x, c = threadIdx.x;
  ushort4 o = make_ushort4(0,0,0,0);
  if (row < DINPROJ){
    float4 f = W[(size_t)row*256 + c];
    o = make_ushort4(f2bf(f.x), f2bf(f.y), f2bf(f.z), f2bf(f.w));
  }
  Wp[(size_t)row*256 + c] = o;
}

// ---- async global->LDS, 16B per lane ----
__device__ __forceinline__ void gld16(const void* g, void* l){
  __builtin_amdgcn_global_load_lds((const __attribute__((address_space(1))) void*)g,
                                   (__attribute__((address_space(3))) void*)l, 16, 0, 0);
}

#define BM 64
#define BN 128
#define BK 32

// ---- bf16 MFMA GEMM: C_f32[m,n] = A[clamp(grow0+m)][:K] . W[n][:K] ----
// global_load_lds staging, double-buffered LDS, one barrier per K-step.
__global__ __launch_bounds__(256) void gemm_bt2(
    const ushort* __restrict__ A, int lda, long grow0, long rowmax,
    const ushort* __restrict__ W, int ldw,
    float* __restrict__ C, int ldc, int K){
  __shared__ ushort As[2][BM*BK];   // [64][32] per buf, linear (gld_lds requires)
  __shared__ ushort Bs[2][BN*BK];   // [128][32] per buf
  const int tid = threadIdx.x;
  const int lane = tid & 63, wave = tid >> 6;
  const int wm = wave >> 1, wn = wave & 1;
  const int m0 = blockIdx.y * BM, n0 = blockIdx.x * BN;
  const int srow = tid >> 2, scol = (tid & 3) * 8;
  long gar = grow0 + m0 + srow;
  if (gar < 0) gar = 0; if (gar > rowmax) gar = rowmax;
  const ushort* gA  = A + gar*(long)lda + scol;
  const ushort* gB0 = W + (size_t)(n0 + srow)*ldw + scol;
  const ushort* gB1 = W + (size_t)(n0 + 64 + srow)*ldw + scol;
  // wave-uniform LDS dests: HW writes base + lane*16B
  ushort* lA  = &As[0][0] + (size_t)wave*512;
  ushort* lB0 = &Bs[0][0] + (size_t)wave*512;
  ushort* lB1 = &Bs[0][0] + 2048 + (size_t)wave*512;
  const int fr = lane & 15, kq = (lane >> 4) * 8;
  f32x4 acc[2][4] = {};

  gld16(gA, lA); gld16(gB0, lB0); gld16(gB1, lB1);
  __syncthreads();
  int cur = 0;
  for (int k0 = 0; k0 < K; k0 += BK){
    int nxt = k0 + BK;
    if (nxt < K){
      int nb = cur ^ 1;
      gld16(gA  + nxt, lA  + nb*(BM*BK));
      gld16(gB0 + nxt, lB0 + nb*(BN*BK));
      gld16(gB1 + nxt, lB1 + nb*(BN*BK));
    }
    const ushort* Ab = &As[cur][0];
    const ushort* Bb = &Bs[cur][0];
    bf16x8 af[2], bw[4];
    #pragma unroll
    for (int i=0;i<2;i++) af[i] = *(const bf16x8*)(Ab + (wm*32 + i*16 + fr)*BK + kq);
    #pragma unroll
    for (int j=0;j<4;j++) bw[j] = *(const bf16x8*)(Bb + (wn*64 + j*16 + fr)*BK + kq);
    #pragma unroll
    for (int i=0;i<2;i++)
      #pragma unroll
      for (int j=0;j<4;j++)
        acc[i][j] = __builtin_amdgcn_mfma_f32_16x16x32_bf16(af[i], bw[j], acc[i][j], 0,0,0);
    if (nxt < K){ __syncthreads(); cur ^= 1; }
  }
  const int crow = (lane >> 4) * 4, cn = lane & 15;
  #pragma unroll
  for (int i=0;i<2;i++)
    #pragma unroll
    for (int j=0;j<4;j++){
      long base = (long)(m0 + wm*32 + i*16 + crow)*ldc + (n0 + wn*64 + j*16 + cn);
      #pragma unroll
      for (int r=0;r<4;r++)
        C[base + (long)r*ldc] = acc[i][j][r];
    }
}

// ---- depthwise conv4 + bias + SiLU; bf16 out ----
__global__ __launch_bounds__(256) void conv_act(const float* __restrict__ zx,
    const float* __restrict__ cw, const float* __restrict__ cb,
    ushort* __restrict__ xconv, int l0){
  int c = blockIdx.x*256 + threadIdx.x;             // 0..2303
  int by = blockIdx.y;                              // 0..CL-1
  int l = l0 + by;
  float acc = cb[c];
  #pragma unroll
  for (int j=0;j<4;j++){
    if (l - 3 + j >= 0)
      acc = fmaf(zx[(size_t)(by+j)*NPAD + DINNER + c], cw[c*4+j], acc);
  }
  float v = acc / (1.f + expf(-acc));
  xconv[(size_t)by*CONVDIM + c] = f2bf(v);
}

// ---- dt = softplus(dt_raw + bias); la = dt * A (log decay) ----
__global__ __launch_bounds__(256) void dt_f32(const float* __restrict__ zx,
    const float* __restrict__ dtb, const float* __restrict__ alog,
    float* __restrict__ dtv, float* __restrict__ lav){
  int i = blockIdx.x*256 + threadIdx.x;             // < CL*32
  int lr = i >> 5, h = i & 31;
  float xv = zx[(size_t)(lr+3)*NPAD + (DINNER + CONVDIM) + h] + dtb[h];
  float sp = (xv > 20.f) ? xv : log1pf(expf(xv));
  float A = -expf(alog[h]);
  dtv[i] = sp;
  lav[i] = sp * A;
}

// ---- scan phase 1: per (chunk,head) decay prefix + G = X^T.Bw; grid (NC, NHEADS) ----
__global__ __launch_bounds__(256) void scan_pre(const ushort* __restrict__ xcv,
    const float* __restrict__ dtv, const float* __restrict__ lav,
    ushort* __restrict__ gbuf, float* __restrict__ lgbuf){
  const int c = blockIdx.x, h = blockIdx.y;
  const int tid = threadIdx.x, lane = tid & 63, w = tid >> 6;
  const int l15 = lane & 15, quad = lane >> 4, kq = quad*8;
  __shared__ float wsx[Q];
  __shared__ __align__(16) ushort XT[64*72];    // [p][s]
  __shared__ __align__(16) ushort BTw[128*72];  // [n][s], weighted
  const int c0 = c*Q;
  if (tid < 64){
    float la = lav[(size_t)(c0+tid)*NHEADS + h];
    float dt = dtv[(size_t)(c0+tid)*NHEADS + h];
    float v = la;
    #pragma unroll
    for (int off=1; off<64; off<<=1){ float u = __shfl_up(v, off); if (tid >= off) v += u; }
    float tot = __shfl(v, 63);
    wsx[tid] = __expf(tot - v)*dt;
    lgbuf[((size_t)h*NC + c)*Q + tid] = v;
  }
  __syncthreads();
  { int s = tid>>2, pb = (tid&3)*16;
    const ushort* src = xcv + (size_t)(c0+s)*CONVDIM + h*64 + pb;
    ushort tmp[16];
    *(uint4*)tmp     = *(const uint4*)src;
    *(uint4*)(tmp+8) = *(const uint4*)(src+8);
    #pragma unroll
    for (int i=0;i<16;i++) XT[(pb+i)*72 + s] = tmp[i];
  }
  { int s = tid>>2, nb4 = (tid&3)*32;
    const ushort* src = xcv + (size_t)(c0+s)*CONVDIM + DINNER + nb4;
    float wv = wsx[s];
    ushort tmp[32];
    #pragma unroll
    for (int v4=0;v4<4;v4++) *(uint4*)(tmp+v4*8) = *(const uint4*)(src+v4*8);
    #pragma unroll
    for (int i=0;i<32;i++) BTw[(nb4+i)*72 + s] = f2bf(bf2f(tmp[i])*wv);
  }
  __syncthreads();
  f32x4 g[8] = {};
  #pragma unroll
  for (int kb=0;kb<2;kb++){
    bf16x8 afr = *(const bf16x8*)(XT + (16*w + l15)*72 + kb*32 + kq);
    #pragma unroll
    for (int j=0;j<8;j++){
      bf16x8 bfr = *(const bf16x8*)(BTw + (16*j + l15)*72 + kb*32 + kq);
      g[j] = __builtin_amdgcn_mfma_f32_16x16x32_bf16(afr, bfr, g[j], 0,0,0);
    }
  }
  ushort* gdst = gbuf + ((size_t)h*NC + c)*8192;   // [p][n] row-major
  #pragma unroll
  for (int j=0;j<8;j++)
    #pragma unroll
    for (int r=0;r<4;r++)
      gdst[(16*w + quad*4 + r)*128 + 16*j + l15] = f2bf(g[j][r]);
}

// ---- scan phase 2: sequential carry over NC chunks; grid (NHEADS) ----
__global__ __launch_bounds__(256) void scan_carry(const ushort* __restrict__ gbuf,
    const float* __restrict__ lgbuf, ushort* __restrict__ hinit,
    float* __restrict__ hstate, int b, int init){
  const int h = blockIdx.x;
  const int tid = threadIdx.x;
  float hreg[32];
  float* hst = hstate + ((size_t)b*NHEADS + h)*8192 + (size_t)tid*32;
  if (init){
    #pragma unroll
    for (int i=0;i<32;i++) hreg[i] = 0.f;
  } else {
    #pragma unroll
    for (int k=0;k<8;k++){
      float4 v = *(const float4*)(hst + k*4);
      hreg[k*4]=v.x; hreg[k*4+1]=v.y; hreg[k*4+2]=v.z; hreg[k*4+3]=v.w;
    }
  }
  for (int c=0;c<NC;c++){
    const size_t base = ((size_t)h*NC + c)*8192 + (size_t)tid*32;
    ushort* hw = hinit + base;
    #pragma unroll
    for (int k=0;k<4;k++){
      ushort u[8];
      #pragma unroll
      for (int i=0;i<8;i++) u[i] = f2bf(hreg[k*8+i]);
      *(uint4*)(hw + k*8) = *(uint4*)u;
    }
    float e = __expf(lgbuf[((size_t)h*NC + c)*Q + 63]);
    const ushort* gr = gbuf + base;
    #pragma unroll
    for (int k=0;k<4;k++){
      uint4 gu = *(const uint4*)(gr + k*8);
      const ushort* gus = (const ushort*)&gu;
      #pragma unroll
      for (int i=0;i<8;i++) hreg[k*8+i] = fmaf(hreg[k*8+i], e, bf2f(gus[i]));
    }
  }
  #pragma unroll
  for (int k=0;k<8;k++)
    *(float4*)(hst + k*4) = make_float4(hreg[k*4],hreg[k*4+1],hreg[k*4+2],hreg[k*4+3]);
}

// ---- scan phase 3: y = els*(C.h_init) + P.X + Dp*x; grid (NC, NHEADS) ----
__global__ __launch_bounds__(256) void scan_y(const ushort* __restrict__ xcv,
    const float* __restrict__ dtv, const float* __restrict__ lgbuf,
    const ushort* __restrict__ hinit, const float* __restrict__ Dp,
    ushort* __restrict__ yb){
  const int c = blockIdx.x, h = blockIdx.y;
  const int tid = threadIdx.x, lane = tid & 63, w = tid >> 6;
  const int l15 = lane & 15, quad = lane >> 4, kq = quad*8;
  __shared__ float lg[Q], dts[Q], els[Q];
  __shared__ __align__(16) ushort XT[64*72];    // [p][s]
  __shared__ __align__(16) ushort Ps[64*72];    // [t][s]
  const int c0 = c*Q;
  if (tid < 64){
    float v = lgbuf[((size_t)h*NC + c)*Q + tid];
    lg[tid] = v;
    els[tid] = __expf(v);
    dts[tid] = dtv[(size_t)(c0+tid)*NHEADS + h];
  }
  { int s = tid>>2, pb = (tid&3)*16;
    const ushort* src = xcv + (size_t)(c0+s)*CONVDIM + h*64 + pb;
    ushort tmp[16];
    *(uint4*)tmp     = *(const uint4*)src;
    *(uint4*)(tmp+8) = *(const uint4*)(src+8);
    #pragma unroll
    for (int i=0;i<16;i++) XT[(pb+i)*72 + s] = tmp[i];
  }
  __syncthreads();
  // S = C.B^T (wave w -> t-rows 16w), P = S * L * dt -> Ps
  {
    const ushort* Crow = xcv + (size_t)(c0 + 16*w + l15)*CONVDIM + DINNER + DSTATE;
    f32x4 sac[4] = {};
    #pragma unroll
    for (int kb=0;kb<4;kb++){
      bf16x8 afr = *(const bf16x8*)(Crow + kb*32 + kq);
      #pragma unroll
      for (int j=0;j<4;j++){
        const ushort* Brow = xcv + (size_t)(c0 + 16*j + l15)*CONVDIM + DINNER;
        bf16x8 bfr = *(const bf16x8*)(Brow + kb*32 + kq);
        sac[j] = __builtin_amdgcn_mfma_f32_16x16x32_bf16(afr, bfr, sac[j], 0,0,0);
      }
    }
    #pragma unroll
    for (int j=0;j<4;j++){
      int s = 16*j + l15;
      float lgs = lg[s], dtss = dts[s];
      #pragma unroll
      for (int r=0;r<4;r++){
        int t = 16*w + quad*4 + r;
        float val = (t >= s) ? sac[j][r]*__expf(lg[t]-lgs)*dtss : 0.f;
        Ps[t*72 + s] = f2bf(val);
      }
    }
  }
  __syncthreads();
  // y tiles (wave w -> p-tile w)
  {
    const float dph = Dp[h];
    bf16x8 hb[4], xb[2];
    const ushort* hrow = hinit + ((size_t)h*NC + c)*8192 + (16*w + l15)*128;
    #pragma unroll
    for (int kb=0;kb<4;kb++) hb[kb] = *(const bf16x8*)(hrow + kb*32 + kq);
    #pragma unroll
    for (int kb=0;kb<2;kb++) xb[kb] = *(const bf16x8*)(XT + (16*w + l15)*72 + kb*32 + kq);
    #pragma unroll
    for (int i=0;i<4;i++){
      const ushort* Crow = xcv + (size_t)(c0 + 16*i + l15)*CONVDIM + DINNER + DSTATE;
      f32x4 y2 = {};
      #pragma unroll
      for (int kb=0;kb<4;kb++){
        bf16x8 afr = *(const bf16x8*)(Crow + kb*32 + kq);
        y2 = __builtin_amdgcn_mfma_f32_16x16x32_bf16(afr, hb[kb], y2, 0,0,0);
      }
      f32x4 y1 = {};
      #pragma unroll
      for (int kb=0;kb<2;kb++){
        bf16x8 afr = *(const bf16x8*)(Ps + (16*i + l15)*72 + kb*32 + kq);
        y1 = __builtin_amdgcn_mfma_f32_16x16x32_bf16(afr, xb[kb], y1, 0,0,0);
      }
      int p = 16*w + l15;
      #pragma unroll
      for (int r=0;r<4;r++){
        int t = 16*i + quad*4 + r;
        float xv = bf2f(XT[p*72 + t]);
        float yv = y1[r] + els[t]*y2[r] + dph*xv;
        yb[(size_t)(c0 + t)*DINNER + h*64 + p] = f2bf(yv);
      }
    }
  }
}

// ---- y(bf16) *= silu(z); RMSNorm(2048) * norm_w -> yg (bf16) ----
__global__ __launch_bounds__(256) void gate_norm_f32(const ushort* __restrict__ yb,
    const float* __restrict__ zx, const float* __restrict__ nw,
    ushort* __restrict__ yg){
  int lr = blockIdx.x, tid = threadIdx.x;
  int d0 = tid*8;
  const ushort* yrow = yb + (size_t)lr*DINNER;
  const float* zrow = zx + (size_t)(lr+3)*NPAD;
  float y[8]; float ss = 0.f;
  #pragma unroll
  for (int i=0;i<8;i++){
    float z = zrow[d0+i];
    float g = z / (1.f + expf(-z));
    float v = bf2f(yrow[d0+i]) * g;
    y[i] = v; ss += v*v;
  }
  #pragma unroll
  for (int m=1;m<64;m<<=1) ss += __shfl_xor(ss, m);
  __shared__ float red[4];
  if ((tid & 63) == 0) red[tid>>6] = ss;
  __syncthreads();
  ss = red[0]+red[1]+red[2]+red[3];
  float scale = rsqrtf(ss * (1.f/DINNER) + 1e-5f);
  ushort* out = yg + (size_t)lr*DINNER;
  #pragma unroll
  for (int i=0;i<8;i++)
    out[d0+i] = f2bf(y[i] * scale * nw[d0+i]);
}

extern "C" void kernel_launch(void* const* d_in, const int* in_sizes, int n_in,
                              void* d_out, int out_size, void* d_ws, size_t ws_size,
                              hipStream_t stream) {
  const float* x    = (const float*)d_in[0];
  const float* ipw  = (const float*)d_in[1];
  const float* cw   = (const float*)d_in[2];
  const float* cb   = (const float*)d_in[3];
  const float* dtb  = (const float*)d_in[4];
  const float* alog = (const float*)d_in[5];
  const float* Dp   = (const float*)d_in[6];
  const float* nw   = (const float*)d_in[7];
  const float* opw  = (const float*)d_in[8];
  char* ws = (char*)d_ws;
  size_t off = 0;
  ushort* xbf    = (ushort*)(ws + off); off += (size_t)ROWS*DMODEL*2;      // 16.8 MB
  ushort* Wp     = (ushort*)(ws + off); off += (size_t)NPAD*DMODEL*2;      //  9.2 MB
  ushort* opwb   = (ushort*)(ws + off); off += (size_t)DMODEL*DINNER*2;    //  4.2 MB
  float*  zxb    = (float*)(ws + off);  off += (size_t)CR*NPAD*4;          // 20.6 MB
  ushort* xconv  = (ushort*)(ws + off); off += (size_t)CL*CONVDIM*2;       //  4.7 MB
  float*  dtv    = (float*)(ws + off);  off += (size_t)CL*NHEADS*4;        //  0.13 MB
  float*  lav    = (float*)(ws + off);  off += (size_t)CL*NHEADS*4;        //  0.13 MB
  ushort* yb     = (ushort*)(ws + off); off += (size_t)CL*DINNER*2;        //  4.2 MB
  ushort* gbuf   = (ushort*)(ws + off); off += (size_t)NHEADS*NC*8192*2;   //  8.4 MB
  ushort* hinit  = (ushort*)(ws + off); off += (size_t)NHEADS*NC*8192*2;   //  8.4 MB
  float*  lgbuf  = (float*)(ws + off);  off += (size_t)NHEADS*NC*Q*4;      //  0.13 MB
  float*  hstate = (float*)(ws + off);  off += (size_t)2*NHEADS*8192*4;    //  2.1 MB
  // yg: if workspace allows, hold ALL chunks' normed activations so the
  // out-proj GEMM runs once at grid (8,128)=1024 blocks instead of 8x 128-block
  // launches. Needs 33.5 MB instead of 4.2 MB.
  int bg2 = (ws_size >= off + (size_t)ROWS*DINNER*2) ? 1 : 0;
  ushort* yg = (ushort*)(ws + off);

  cvt_k<<<ROWS*DMODEL/8/256, 256, 0, stream>>>((const float4*)x, (uint4*)xbf);
  padw_cvt<<<NPAD, 256, 0, stream>>>((const float4*)ipw, (ushort4*)Wp);
  cvt_k<<<DMODEL*DINNER/8/256, 256, 0, stream>>>((const float4*)opw, (uint4*)opwb);

  for (int ck = 0; ck < 8; ck++){
    int b  = ck >> 2;
    int l0 = (ck & 3) * CL;
    long grow0 = (long)b*LL + l0 - 3;
    ushort* ygck = yg + (bg2 ? (size_t)ck*CL*DINNER : 0);
    gemm_bt2<<<dim3(NPAD/BN, CR/BM), 256, 0, stream>>>(
        xbf, DMODEL, grow0, (long)ROWS-1, Wp, DMODEL, zxb, NPAD, DMODEL);
    conv_act<<<dim3(CONVDIM/256, CL), 256, 0, stream>>>(zxb, cw, cb, xconv, l0);
    dt_f32<<<CL*NHEADS/256, 256, 0, stream>>>(zxb, dtb, alog, dtv, lav);
    scan_pre<<<dim3(NC, NHEADS), 256, 0, stream>>>(xconv, dtv, lav, gbuf, lgbuf);
    scan_carry<<<NHEADS, 256, 0, stream>>>(gbuf, lgbuf, hinit, hstate, b, (l0==0)?1:0);
    scan_y<<<dim3(NC, NHEADS), 256, 0, stream>>>(xconv, dtv, lgbuf, hinit, Dp, yb);
    gate_norm_f32<<<CL, 256, 0, stream>>>(yb, zxb, nw, ygck);
    if (!bg2)
      gemm_bt2<<<dim3(DMODEL/BN, CL/BM), 256, 0, stream>>>(
          ygck, DINNER, 0, (long)CL-1, opwb, DINNER,
          (float*)d_out + (size_t)(b*LL + l0)*DMODEL, DMODEL, DINNER);
  }
  if (bg2)
    gemm_bt2<<<dim3(DMODEL/BN, ROWS/BM), 256, 0, stream>>>(
        yg, DINNER, 0, (long)ROWS-1, opwb, DINNER,
        (float*)d_out, DMODEL, DINNER);
}

// Round 2
// 860.407 us; speedup vs baseline: 1.4629x; 1.0547x over previous
//
#include <hip/hip_runtime.h>

#define LL 4096
#define DMODEL 1024
#define DINNER 2048
#define NHEADS 32
#define DSTATE 128
#define DINPROJ 4384
#define NPAD 4480          // 35*128 padded gemm1 N; zxb f32 row stride
#define CONVDIM 2304
#define ROWS 8192
#define CL 1024            // rows per L-chunk
#define CR 1152            // 9*128 rows computed by gemm1 per chunk (CL + 3 halo)
#define Q 64               // scan sub-chunk
#define NC 16              // sub-chunks per scan launch (CL/Q)

typedef __attribute__((ext_vector_type(8))) __bf16 bf16x8;
typedef __attribute__((ext_vector_type(4))) float f32x4;

__device__ __forceinline__ float bf2f(ushort u){ union{uint i;float f;} v; v.i=(uint)u<<16; return v.f; }
__device__ __forceinline__ ushort f2bf(float f){ union{float f;uint i;} v; v.f=f; uint r=v.i+0x7fffu+((v.i>>16)&1u); return (ushort)(r>>16); }

// ---- f32 -> bf16, 8 elems/thread ----
__global__ __launch_bounds__(256) void cvt_k(const float4* __restrict__ src, uint4* __restrict__ dst){
  long t = (long)blockIdx.x*256 + threadIdx.x;
  float4 a = src[t*2], b = src[t*2+1];
  ushort u[8] = { f2bf(a.x),f2bf(a.y),f2bf(a.z),f2bf(a.w),
                  f2bf(b.x),f2bf(b.y),f2bf(b.z),f2bf(b.w) };
  dst[t] = *(uint4*)u;
}

// ---- in_proj_w f32 (4384x1024) -> padded bf16 (4480x1024) ----
__global__ __launch_bounds__(256) void padw_cvt(const float4* __restrict__ W, ushort4* __restrict__ Wp){
  int row = blockIdx.x, c = threadIdx.x;
  ushort4 o = make_ushort4(0,0,0,0);
  if (row < DINPROJ){
    float4 f = W[(size_t)row*256 + c];
    o = make_ushort4(f2bf(f.x), f2bf(f.y), f2bf(f.z), f2bf(f.w));
  }
  Wp[(size_t)row*256 + c] = o;
}

// ---- async global->LDS, 16B per lane ----
__device__ __forceinline__ void gld16(const void* g, void* l){
  __builtin_amdgcn_global_load_lds((const __attribute__((address_space(1))) void*)g,
                                   (__attribute__((address_space(3))) void*)l, 16, 0, 0);
}

#define BM 64
#define BN 128
#define BK 64

// ---- bf16 MFMA GEMM: C_f32[m,n] = A[clamp(grow0+m)][:K] . W[n][:K] ----
// global_load_lds staging (linear dest), XOR-swizzled global source +
// XOR-swizzled ds_read (st_16x32 pattern: 128B rows, slot ^= row&7).
// Double-buffered LDS, one barrier per K-step of 64.
// swz=1: bijective XCD-chunked n-major block swizzle (q=nwg/8, r=nwg%8).
__global__ __launch_bounds__(256) void gemm_bt3(
    const ushort* __restrict__ A, int lda, long grow0, long rowmax,
    const ushort* __restrict__ W, int ldw,
    float* __restrict__ C, int ldc, int K, int swz, int q, int r){
  __shared__ ushort As[2][BM*BK];   // 8 KB per buf
  __shared__ ushort Bs[2][BN*BK];   // 16 KB per buf
  const int tid = threadIdx.x;
  const int lane = tid & 63, wave = tid >> 6;
  const int wm = wave >> 1, wn = wave & 1;
  int bx, by;
  if (swz){
    int wgid = blockIdx.y * gridDim.x + blockIdx.x;
    int xcd = wgid & 7, i = wgid >> 3;
    int vid = (xcd < r) ? xcd*(q+1) + i : r*(q+1) + (xcd - r)*q + i;
    bx = vid / (int)gridDim.y;  by = vid % (int)gridDim.y;   // n-major: XCD owns contiguous n-cols
  } else { bx = blockIdx.x; by = blockIdx.y; }
  const int m0 = by * BM, n0 = bx * BN;

  // staging geometry: lane -> (row-in-8, slot 0..7 of 16B within 128B row)
  const int sl = lane & 7;           // dest slot
  const int srw = lane >> 3;         // dest row within wave's 8-row stripe
  const int scol = ((sl ^ (srw & 7)) * 8);   // inverse-swizzled source col (elements)

  // A: 2 rounds of 8-row stripes per wave (rows 32*rr + 8*wave + srw)
  const ushort* gA[2];
  #pragma unroll
  for (int rr=0; rr<2; rr++){
    long gr = grow0 + m0 + 32*rr + 8*wave + srw;
    if (gr < 0) gr = 0; if (gr > rowmax) gr = rowmax;
    gA[rr] = A + gr*(long)lda + scol;
  }
  // B: 4 rounds
  const ushort* gB[4];
  #pragma unroll
  for (int rr=0; rr<4; rr++)
    gB[rr] = W + (size_t)(n0 + 32*rr + 8*wave + srw)*ldw + scol;

  // wave-uniform linear LDS dests (HW writes base + lane*16B)
  ushort* lA[2]; ushort* lB[4];
  #pragma unroll
  for (int rr=0; rr<2; rr++) lA[rr] = &As[0][0] + (32*rr + 8*wave)*BK;
  #pragma unroll
  for (int rr=0; rr<4; rr++) lB[rr] = &Bs[0][0] + (32*rr + 8*wave)*BK;

  const int fr = lane & 15, quad = lane >> 4;
  f32x4 acc[2][4] = {};

  // prologue stage buf 0
  #pragma unroll
  for (int rr=0; rr<2; rr++) gld16(gA[rr], lA[rr]);
  #pragma unroll
  for (int rr=0; rr<4; rr++) gld16(gB[rr], lB[rr]);
  __syncthreads();

  int cur = 0;
  for (int k0 = 0; k0 < K; k0 += BK){
    int nxt = k0 + BK;
    if (nxt < K){
      int nb = cur ^ 1;
      #pragma unroll
      for (int rr=0; rr<2; rr++) gld16(gA[rr] + nxt, lA[rr] + nb*(BM*BK));
      #pragma unroll
      for (int rr=0; rr<4; rr++) gld16(gB[rr] + nxt, lB[rr] + nb*(BN*BK));
    }
    const ushort* Ab = &As[cur][0];
    const ushort* Bb = &Bs[cur][0];
    #pragma unroll
    for (int kb=0; kb<2; kb++){
      const int es = ((kb*4 + quad) ^ (fr & 7)) * 8;   // swizzled slot (elements)
      bf16x8 af[2], bw[4];
      #pragma unroll
      for (int i=0;i<2;i++) af[i] = *(const bf16x8*)(Ab + (wm*32 + i*16 + fr)*BK + es);
      #pragma unroll
      for (int j=0;j<4;j++) bw[j] = *(const bf16x8*)(Bb + (wn*64 + j*16 + fr)*BK + es);
      #pragma unroll
      for (int i=0;i<2;i++)
        #pragma unroll
        for (int j=0;j<4;j++)
          acc[i][j] = __builtin_amdgcn_mfma_f32_16x16x32_bf16(af[i], bw[j], acc[i][j], 0,0,0);
    }
    if (nxt < K){ __syncthreads(); cur ^= 1; }
  }
  const int crow = quad * 4, cn = fr;
  #pragma unroll
  for (int i=0;i<2;i++)
    #pragma unroll
    for (int j=0;j<4;j++){
      long base = (long)(m0 + wm*32 + i*16 + crow)*ldc + (n0 + wn*64 + j*16 + cn);
      #pragma unroll
      for (int rr=0;rr<4;rr++)
        __builtin_nontemporal_store(acc[i][j][rr], C + base + (long)rr*ldc);
    }
}

// ---- depthwise conv4 + bias + SiLU; bf16 out ----
__global__ __launch_bounds__(256) void conv_act(const float* __restrict__ zx,
    const float* __restrict__ cw, const float* __restrict__ cb,
    ushort* __restrict__ xconv, int l0){
  int c = blockIdx.x*256 + threadIdx.x;             // 0..2303
  int by = blockIdx.y;                              // 0..CL-1
  int l = l0 + by;
  float acc = cb[c];
  #pragma unroll
  for (int j=0;j<4;j++){
    if (l - 3 + j >= 0)
      acc = fmaf(zx[(size_t)(by+j)*NPAD + DINNER + c], cw[c*4+j], acc);
  }
  float v = acc / (1.f + expf(-acc));
  xconv[(size_t)by*CONVDIM + c] = f2bf(v);
}

// ---- dt = softplus(dt_raw + bias); la = dt * A (log decay) ----
__global__ __launch_bounds__(256) void dt_f32(const float* __restrict__ zx,
    const float* __restrict__ dtb, const float* __restrict__ alog,
    float* __restrict__ dtv, float* __restrict__ lav){
  int i = blockIdx.x*256 + threadIdx.x;             // < CL*32
  int lr = i >> 5, h = i & 31;
  float xv = zx[(size_t)(lr+3)*NPAD + (DINNER + CONVDIM) + h] + dtb[h];
  float sp = (xv > 20.f) ? xv : log1pf(expf(xv));
  float A = -expf(alog[h]);
  dtv[i] = sp;
  lav[i] = sp * A;
}

// ---- scan phase 1: per (chunk,head) decay prefix + G = X^T.Bw; grid (NC, NHEADS) ----
__global__ __launch_bounds__(256) void scan_pre(const ushort* __restrict__ xcv,
    const float* __restrict__ dtv, const float* __restrict__ lav,
    ushort* __restrict__ gbuf, float* __restrict__ lgbuf){
  const int c = blockIdx.x, h = blockIdx.y;
  const int tid = threadIdx.x, lane = tid & 63, w = tid >> 6;
  const int l15 = lane & 15, quad = lane >> 4, kq = quad*8;
  __shared__ float wsx[Q];
  __shared__ __align__(16) ushort XT[64*72];    // [p][s]
  __shared__ __align__(16) ushort BTw[128*72];  // [n][s], weighted
  const int c0 = c*Q;
  if (tid < 64){
    float la = lav[(size_t)(c0+tid)*NHEADS + h];
    float dt = dtv[(size_t)(c0+tid)*NHEADS + h];
    float v = la;
    #pragma unroll
    for (int off=1; off<64; off<<=1){ float u = __shfl_up(v, off); if (tid >= off) v += u; }
    float tot = __shfl(v, 63);
    wsx[tid] = __expf(tot - v)*dt;
    lgbuf[((size_t)h*NC + c)*Q + tid] = v;
  }
  __syncthreads();
  { int s = tid>>2, pb = (tid&3)*16;
    const ushort* src = xcv + (size_t)(c0+s)*CONVDIM + h*64 + pb;
    ushort tmp[16];
    *(uint4*)tmp     = *(const uint4*)src;
    *(uint4*)(tmp+8) = *(const uint4*)(src+8);
    #pragma unroll
    for (int i=0;i<16;i++) XT[(pb+i)*72 + s] = tmp[i];
  }
  { int s = tid>>2, nb4 = (tid&3)*32;
    const ushort* src = xcv + (size_t)(c0+s)*CONVDIM + DINNER + nb4;
    float wv = wsx[s];
    ushort tmp[32];
    #pragma unroll
    for (int v4=0;v4<4;v4++) *(uint4*)(tmp+v4*8) = *(const uint4*)(src+v4*8);
    #pragma unroll
    for (int i=0;i<32;i++) BTw[(nb4+i)*72 + s] = f2bf(bf2f(tmp[i])*wv);
  }
  __syncthreads();
  f32x4 g[8] = {};
  #pragma unroll
  for (int kb=0;kb<2;kb++){
    bf16x8 afr = *(const bf16x8*)(XT + (16*w + l15)*72 + kb*32 + kq);
    #pragma unroll
    for (int j=0;j<8;j++){
      bf16x8 bfr = *(const bf16x8*)(BTw + (16*j + l15)*72 + kb*32 + kq);
      g[j] = __builtin_amdgcn_mfma_f32_16x16x32_bf16(afr, bfr, g[j], 0,0,0);
    }
  }
  ushort* gdst = gbuf + ((size_t)h*NC + c)*8192;   // [p][n] row-major
  #pragma unroll
  for (int j=0;j<8;j++)
    #pragma unroll
    for (int r=0;r<4;r++)
      gdst[(16*w + quad*4 + r)*128 + 16*j + l15] = f2bf(g[j][r]);
}

// ---- scan phase 2: sequential carry over NC chunks; grid (NHEADS) ----
__global__ __launch_bounds__(256) void scan_carry(const ushort* __restrict__ gbuf,
    const float* __restrict__ lgbuf, ushort* __restrict__ hinit,
    float* __restrict__ hstate, int b, int init){
  const int h = blockIdx.x;
  const int tid = threadIdx.x;
  float hreg[32];
  float* hst = hstate + ((size_t)b*NHEADS + h)*8192 + (size_t)tid*32;
  if (init){
    #pragma unroll
    for (int i=0;i<32;i++) hreg[i] = 0.f;
  } else {
    #pragma unroll
    for (int k=0;k<8;k++){
      float4 v = *(const float4*)(hst + k*4);
      hreg[k*4]=v.x; hreg[k*4+1]=v.y; hreg[k*4+2]=v.z; hreg[k*4+3]=v.w;
    }
  }
  for (int c=0;c<NC;c++){
    const size_t base = ((size_t)h*NC + c)*8192 + (size_t)tid*32;
    ushort* hw = hinit + base;
    #pragma unroll
    for (int k=0;k<4;k++){
      ushort u[8];
      #pragma unroll
      for (int i=0;i<8;i++) u[i] = f2bf(hreg[k*8+i]);
      *(uint4*)(hw + k*8) = *(uint4*)u;
    }
    float e = __expf(lgbuf[((size_t)h*NC + c)*Q + 63]);
    const ushort* gr = gbuf + base;
    #pragma unroll
    for (int k=0;k<4;k++){
      uint4 gu = *(const uint4*)(gr + k*8);
      const ushort* gus = (const ushort*)&gu;
      #pragma unroll
      for (int i=0;i<8;i++) hreg[k*8+i] = fmaf(hreg[k*8+i], e, bf2f(gus[i]));
    }
  }
  #pragma unroll
  for (int k=0;k<8;k++)
    *(float4*)(hst + k*4) = make_float4(hreg[k*4],hreg[k*4+1],hreg[k*4+2],hreg[k*4+3]);
}

// ---- scan phase 3: y = els*(C.h_init) + P.X + Dp*x; grid (NC, NHEADS) ----
__global__ __launch_bounds__(256) void scan_y(const ushort* __restrict__ xcv,
    const float* __restrict__ dtv, const float* __restrict__ lgbuf,
    const ushort* __restrict__ hinit, const float* __restrict__ Dp,
    ushort* __restrict__ yb){
  const int c = blockIdx.x, h = blockIdx.y;
  const int tid = threadIdx.x, lane = tid & 63, w = tid >> 6;
  const int l15 = lane & 15, quad = lane >> 4, kq = quad*8;
  __shared__ float lg[Q], dts[Q], els[Q];
  __shared__ __align__(16) ushort XT[64*72];    // [p][s]
  __shared__ __align__(16) ushort Ps[64*72];    // [t][s]
  const int c0 = c*Q;
  if (tid < 64){
    float v = lgbuf[((size_t)h*NC + c)*Q + tid];
    lg[tid] = v;
    els[tid] = __expf(v);
    dts[tid] = dtv[(size_t)(c0+tid)*NHEADS + h];
  }
  { int s = tid>>2, pb = (tid&3)*16;
    const ushort* src = xcv + (size_t)(c0+s)*CONVDIM + h*64 + pb;
    ushort tmp[16];
    *(uint4*)tmp     = *(const uint4*)src;
    *(uint4*)(tmp+8) = *(const uint4*)(src+8);
    #pragma unroll
    for (int i=0;i<16;i++) XT[(pb+i)*72 + s] = tmp[i];
  }
  __syncthreads();
  // S = C.B^T (wave w -> t-rows 16w), P = S * L * dt -> Ps
  {
    const ushort* Crow = xcv + (size_t)(c0 + 16*w + l15)*CONVDIM + DINNER + DSTATE;
    f32x4 sac[4] = {};
    #pragma unroll
    for (int kb=0;kb<4;kb++){
      bf16x8 afr = *(const bf16x8*)(Crow + kb*32 + kq);
      #pragma unroll
      for (int j=0;j<4;j++){
        const ushort* Brow = xcv + (size_t)(c0 + 16*j + l15)*CONVDIM + DINNER;
        bf16x8 bfr = *(const bf16x8*)(Brow + kb*32 + kq);
        sac[j] = __builtin_amdgcn_mfma_f32_16x16x32_bf16(afr, bfr, sac[j], 0,0,0);
      }
    }
    #pragma unroll
    for (int j=0;j<4;j++){
      int s = 16*j + l15;
      float lgs = lg[s], dtss = dts[s];
      #pragma unroll
      for (int r=0;r<4;r++){
        int t = 16*w + quad*4 + r;
        float val = (t >= s) ? sac[j][r]*__expf(lg[t]-lgs)*dtss : 0.f;
        Ps[t*72 + s] = f2bf(val);
      }
    }
  }
  __syncthreads();
  // y tiles (wave w -> p-tile w)
  {
    const float dph = Dp[h];
    bf16x8 hb[4], xb[2];
    const ushort* hrow = hinit + ((size_t)h*NC + c)*8192 + (16*w + l15)*128;
    #pragma unroll
    for (int kb=0;kb<4;kb++) hb[kb] = *(const bf16x8*)(hrow + kb*32 + kq);
    #pragma unroll
    for (int kb=0;kb<2;kb++) xb[kb] = *(const bf16x8*)(XT + (16*w + l15)*72 + kb*32 + kq);
    #pragma unroll
    for (int i=0;i<4;i++){
      const ushort* Crow = xcv + (size_t)(c0 + 16*i + l15)*CONVDIM + DINNER + DSTATE;
      f32x4 y2 = {};
      #pragma unroll
      for (int kb=0;kb<4;kb++){
        bf16x8 afr = *(const bf16x8*)(Crow + kb*32 + kq);
        y2 = __builtin_amdgcn_mfma_f32_16x16x32_bf16(afr, hb[kb], y2, 0,0,0);
      }
      f32x4 y1 = {};
      #pragma unroll
      for (int kb=0;kb<2;kb++){
        bf16x8 afr = *(const bf16x8*)(Ps + (16*i + l15)*72 + kb*32 + kq);
        y1 = __builtin_amdgcn_mfma_f32_16x16x32_bf16(afr, xb[kb], y1, 0,0,0);
      }
      int p = 16*w + l15;
      #pragma unroll
      for (int r=0;r<4;r++){
        int t = 16*i + quad*4 + r;
        float xv = bf2f(XT[p*72 + t]);
        float yv = y1[r] + els[t]*y2[r] + dph*xv;
        yb[(size_t)(c0 + t)*DINNER + h*64 + p] = f2bf(yv);
      }
    }
  }
}

// ---- y(bf16) *= silu(z); RMSNorm(2048) * norm_w -> yg (bf16) ----
__global__ __launch_bounds__(256) void gate_norm_f32(const ushort* __restrict__ yb,
    const float* __restrict__ zx, const float* __restrict__ nw,
    ushort* __restrict__ yg){
  int lr = blockIdx.x, tid = threadIdx.x;
  int d0 = tid*8;
  const ushort* yrow = yb + (size_t)lr*DINNER;
  const float* zrow = zx + (size_t)(lr+3)*NPAD;
  float y[8]; float ss = 0.f;
  #pragma unroll
  for (int i=0;i<8;i++){
    float z = zrow[d0+i];
    float g = z / (1.f + expf(-z));
    float v = bf2f(yrow[d0+i]) * g;
    y[i] = v; ss += v*v;
  }
  #pragma unroll
  for (int m=1;m<64;m<<=1) ss += __shfl_xor(ss, m);
  __shared__ float red[4];
  if ((tid & 63) == 0) red[tid>>6] = ss;
  __syncthreads();
  ss = red[0]+red[1]+red[2]+red[3];
  float scale = rsqrtf(ss * (1.f/DINNER) + 1e-5f);
  ushort* out = yg + (size_t)lr*DINNER;
  #pragma unroll
  for (int i=0;i<8;i++)
    out[d0+i] = f2bf(y[i] * scale * nw[d0+i]);
}

extern "C" void kernel_launch(void* const* d_in, const int* in_sizes, int n_in,
                              void* d_out, int out_size, void* d_ws, size_t ws_size,
                              hipStream_t stream) {
  const float* x    = (const float*)d_in[0];
  const float* ipw  = (const float*)d_in[1];
  const float* cw   = (const float*)d_in[2];
  const float* cb   = (const float*)d_in[3];
  const float* dtb  = (const float*)d_in[4];
  const float* alog = (const float*)d_in[5];
  const float* Dp   = (const float*)d_in[6];
  const float* nw   = (const float*)d_in[7];
  const float* opw  = (const float*)d_in[8];
  char* ws = (char*)d_ws;
  size_t off = 0;
  ushort* xbf    = (ushort*)(ws + off); off += (size_t)ROWS*DMODEL*2;      // 16.8 MB
  ushort* Wp     = (ushort*)(ws + off); off += (size_t)NPAD*DMODEL*2;      //  9.2 MB
  ushort* opwb   = (ushort*)(ws + off); off += (size_t)DMODEL*DINNER*2;    //  4.2 MB
  float*  zxb    = (float*)(ws + off);  off += (size_t)CR*NPAD*4;          // 20.6 MB
  ushort* xconv  = (ushort*)(ws + off); off += (size_t)CL*CONVDIM*2;       //  4.7 MB
  float*  dtv    = (float*)(ws + off);  off += (size_t)CL*NHEADS*4;        //  0.13 MB
  float*  lav    = (float*)(ws + off);  off += (size_t)CL*NHEADS*4;        //  0.13 MB
  ushort* yb     = (ushort*)(ws + off); off += (size_t)CL*DINNER*2;        //  4.2 MB
  ushort* gbuf   = (ushort*)(ws + off); off += (size_t)NHEADS*NC*8192*2;   //  8.4 MB
  ushort* hinit  = (ushort*)(ws + off); off += (size_t)NHEADS*NC*8192*2;   //  8.4 MB
  float*  lgbuf  = (float*)(ws + off);  off += (size_t)NHEADS*NC*Q*4;      //  0.13 MB
  float*  hstate = (float*)(ws + off);  off += (size_t)2*NHEADS*8192*4;    //  2.1 MB
  // yg: if workspace allows, hold ALL chunks' normed activations so the
  // out-proj GEMM runs once at grid (8,128)=1024 blocks instead of 8x 128-block
  // launches. Needs 33.5 MB instead of 4.2 MB.
  int bg2 = (ws_size >= off + (size_t)ROWS*DINNER*2) ? 1 : 0;
  ushort* yg = (ushort*)(ws + off);

  cvt_k<<<ROWS*DMODEL/8/256, 256, 0, stream>>>((const float4*)x, (uint4*)xbf);
  padw_cvt<<<NPAD, 256, 0, stream>>>((const float4*)ipw, (ushort4*)Wp);
  cvt_k<<<DMODEL*DINNER/8/256, 256, 0, stream>>>((const float4*)opw, (uint4*)opwb);

  const int nwg1 = (NPAD/BN)*(CR/BM);          // 630
  const int q1 = nwg1/8, r1 = nwg1%8;

  for (int ck = 0; ck < 8; ck++){
    int b  = ck >> 2;
    int l0 = (ck & 3) * CL;
    long grow0 = (long)b*LL + l0 - 3;
    ushort* ygck = yg + (bg2 ? (size_t)ck*CL*DINNER : 0);
    gemm_bt3<<<dim3(NPAD/BN, CR/BM), 256, 0, stream>>>(
        xbf, DMODEL, grow0, (long)ROWS-1, Wp, DMODEL, zxb, NPAD, DMODEL, 1, q1, r1);
    conv_act<<<dim3(CONVDIM/256, CL), 256, 0, stream>>>(zxb, cw, cb, xconv, l0);
    dt_f32<<<CL*NHEADS/256, 256, 0, stream>>>(zxb, dtb, alog, dtv, lav);
    scan_pre<<<dim3(NC, NHEADS), 256, 0, stream>>>(xconv, dtv, lav, gbuf, lgbuf);
    scan_carry<<<NHEADS, 256, 0, stream>>>(gbuf, lgbuf, hinit, hstate, b, (l0==0)?1:0);
    scan_y<<<dim3(NC, NHEADS), 256, 0, stream>>>(xconv, dtv, lgbuf, hinit, Dp, yb);
    gate_norm_f32<<<CL, 256, 0, stream>>>(yb, zxb, nw, ygck);
    if (!bg2)
      gemm_bt3<<<dim3(DMODEL/BN, CL/BM), 256, 0, stream>>>(
          ygck, DINNER, 0, (long)CL-1, opwb, DINNER,
          (float*)d_out + (size_t)(b*LL + l0)*DMODEL, DMODEL, DINNER, 0, 0, 0);
  }
  if (bg2)
    gemm_bt3<<<dim3(DMODEL/BN, ROWS/BM), 256, 0, stream>>>(
        yg, DINNER, 0, (long)ROWS-1, opwb, DINNER,
        (float*)d_out, DMODEL, DINNER, 0, 0, 0);
}

// Round 3
// 757.041 us; speedup vs baseline: 1.6626x; 1.1365x over previous
//
#include <hip/hip_runtime.h>

#define LL 4096
#define DMODEL 1024
#define DINNER 2048
#define NHEADS 32
#define DSTATE 128
#define DINPROJ 4384
#define NZX 4352           // zxbh bf16 row stride (34*128: z + xBC cols)
#define CONVDIM 2304
#define ROWS 8192
#define CL 1024            // rows per scan L-chunk
#define Q 64               // scan sub-chunk
#define NC 16              // sub-chunks per scan launch (CL/Q)

typedef __attribute__((ext_vector_type(8))) __bf16 bf16x8;
typedef __attribute__((ext_vector_type(4))) float f32x4;

__device__ __forceinline__ float bf2f(ushort u){ union{uint i;float f;} v; v.i=(uint)u<<16; return v.f; }
__device__ __forceinline__ ushort f2bf(float f){ union{float f;uint i;} v; v.f=f; uint r=v.i+0x7fffu+((v.i>>16)&1u); return (ushort)(r>>16); }

// ---- f32 -> bf16, 8 elems/thread ----
__global__ __launch_bounds__(256) void cvt_k(const float4* __restrict__ src, uint4* __restrict__ dst){
  long t = (long)blockIdx.x*256 + threadIdx.x;
  float4 a = src[t*2], b = src[t*2+1];
  ushort u[8] = { f2bf(a.x),f2bf(a.y),f2bf(a.z),f2bf(a.w),
                  f2bf(b.x),f2bf(b.y),f2bf(b.z),f2bf(b.w) };
  dst[t] = *(uint4*)u;
}

// ---- in_proj_w f32 (4384x1024) -> padded bf16 (4480x1024) ----
__global__ __launch_bounds__(256) void padw_cvt(const float4* __restrict__ W, ushort4* __restrict__ Wp){
  int row = blockIdx.x, c = threadIdx.x;
  ushort4 o = make_ushort4(0,0,0,0);
  if (row < DINPROJ){
    float4 f = W[(size_t)row*256 + c];
    o = make_ushort4(f2bf(f.x), f2bf(f.y), f2bf(f.z), f2bf(f.w));
  }
  Wp[(size_t)row*256 + c] = o;
}

// ---- async global->LDS, 16B per lane ----
__device__ __forceinline__ void gld16(const void* g, void* l){
  __builtin_amdgcn_global_load_lds((const __attribute__((address_space(1))) void*)g,
                                   (__attribute__((address_space(3))) void*)l, 16, 0, 0);
}

#define GBM 128
#define GBN 128
#define GBK 32

// ---- bf16 MFMA GEMM: C[m,n] = A[clamp(grow0+m)][:K] . W[n][:K] ----
// 128x128 tile, BK=32, double-buffered gld_lds staging (linear dest),
// XOR swizzle slot^=((row>>1)&3) on both global-source and ds_read sides
// (conflict-free, <=2-way). obf: 1 -> bf16 C, 0 -> f32 C.
// swz=1: bijective m-major XCD chunking (q=nwg/8, r=nwg%8).
__global__ __launch_bounds__(256) void gemm_tile(
    const ushort* __restrict__ A, int lda, long grow0, long rowmax,
    const ushort* __restrict__ W, int ldw,
    void* __restrict__ Cv, int ldc, int K, int obf, int swz, int q, int r){
  __shared__ __align__(16) ushort As[2][GBM*GBK];   // 16 KB
  __shared__ __align__(16) ushort Bs[2][GBN*GBK];   // 16 KB
  const int tid = threadIdx.x;
  const int lane = tid & 63, wave = tid >> 6;
  const int wm = wave >> 1, wn = wave & 1;
  int bx, by;
  if (swz){
    int wgid = blockIdx.y * gridDim.x + blockIdx.x;
    int xcd = wgid & 7, i = wgid >> 3;
    int vid = (xcd < r) ? xcd*(q+1) + i : r*(q+1) + (xcd - r)*q + i;
    by = vid / (int)gridDim.x;  bx = vid % (int)gridDim.x;   // m-major: XCD owns contiguous m-bands
  } else { bx = blockIdx.x; by = blockIdx.y; }
  const int m0 = by * GBM, n0 = bx * GBN;

  // staging: lane -> row 16*wave + (lane>>2), dest slot lane&3 (16B units);
  // source col pre-swizzled so LDS slot sd holds col (sd ^ ((row>>1)&3)).
  const int srow = lane >> 2;                            // 0..15
  const int scol = (((lane & 3) ^ ((lane >> 3) & 3)) * 8);
  long ra0 = grow0 + m0 + 16*wave + srow;      if (ra0 < 0) ra0 = 0; if (ra0 > rowmax) ra0 = rowmax;
  long ra1 = grow0 + m0 + 64 + 16*wave + srow; if (ra1 < 0) ra1 = 0; if (ra1 > rowmax) ra1 = rowmax;
  const ushort* gA0 = A + ra0*(long)lda + scol;
  const ushort* gA1 = A + ra1*(long)lda + scol;
  const ushort* gB0 = W + (size_t)(n0 + 16*wave + srow)*ldw + scol;
  const ushort* gB1 = W + (size_t)(n0 + 64 + 16*wave + srow)*ldw + scol;
  // wave-uniform linear LDS dests (HW writes base + lane*16B)
  ushort* lA0 = &As[0][0] + (16*wave)*GBK;
  ushort* lA1 = &As[0][0] + (64 + 16*wave)*GBK;
  ushort* lB0 = &Bs[0][0] + (16*wave)*GBK;
  ushort* lB1 = &Bs[0][0] + (64 + 16*wave)*GBK;

  const int fr = lane & 15, quad = lane >> 4;
  const int es = ((quad ^ ((fr >> 1) & 3)) * 8);   // swizzled k-slot for ds_read
  f32x4 acc[4][4] = {};

#define STAGE(buf, ko) { \
    gld16(gA0 + (ko), lA0 + (buf)*(GBM*GBK)); \
    gld16(gA1 + (ko), lA1 + (buf)*(GBM*GBK)); \
    gld16(gB0 + (ko), lB0 + (buf)*(GBN*GBK)); \
    gld16(gB1 + (ko), lB1 + (buf)*(GBN*GBK)); }

  STAGE(0, 0);
  __syncthreads();
  int cur = 0;
  const int nst = K / GBK;
  for (int s = 0; s < nst; ++s){
    if (s + 1 < nst) STAGE(cur^1, (s+1)*GBK);
    const ushort* Ab = &As[cur][0];
    const ushort* Bb = &Bs[cur][0];
    bf16x8 af[4], bw[4];
    #pragma unroll
    for (int i=0;i<4;i++) af[i] = *(const bf16x8*)(Ab + (wm*64 + i*16 + fr)*GBK + es);
    #pragma unroll
    for (int j=0;j<4;j++) bw[j] = *(const bf16x8*)(Bb + (wn*64 + j*16 + fr)*GBK + es);
    #pragma unroll
    for (int i=0;i<4;i++)
      #pragma unroll
      for (int j=0;j<4;j++)
        acc[i][j] = __builtin_amdgcn_mfma_f32_16x16x32_bf16(af[i], bw[j], acc[i][j], 0,0,0);
    if (s + 1 < nst){ __syncthreads(); cur ^= 1; }
  }
#undef STAGE
  if (obf){
    ushort* Cb = (ushort*)Cv;
    #pragma unroll
    for (int i=0;i<4;i++)
      #pragma unroll
      for (int j=0;j<4;j++){
        size_t base = (size_t)(m0 + wm*64 + i*16 + quad*4)*ldc + (n0 + wn*64 + j*16 + fr);
        #pragma unroll
        for (int rr=0;rr<4;rr++)
          Cb[base + (size_t)rr*ldc] = f2bf(acc[i][j][rr]);
      }
  } else {
    float* Cf = (float*)Cv;
    #pragma unroll
    for (int i=0;i<4;i++)
      #pragma unroll
      for (int j=0;j<4;j++){
        size_t base = (size_t)(m0 + wm*64 + i*16 + quad*4)*ldc + (n0 + wn*64 + j*16 + fr);
        #pragma unroll
        for (int rr=0;rr<4;rr++)
          Cf[base + (size_t)rr*ldc] = acc[i][j][rr];
      }
  }
}

// ---- depthwise conv4 + bias + SiLU from bf16 zxbh; bf16 out ----
// row index into zxbh = base + by - 3 + j; within-seq position l = (l0+by)&4095
__global__ __launch_bounds__(256) void conv_act(const ushort* __restrict__ zxh,
    const float* __restrict__ cw, const float* __restrict__ cb,
    ushort* __restrict__ xconv, int l0, long base){
  int c = blockIdx.x*256 + threadIdx.x;             // 0..2303
  int by = blockIdx.y;
  int l = (l0 + by) & (LL-1);
  float acc = cb[c];
  #pragma unroll
  for (int j=0;j<4;j++){
    if (l - 3 + j >= 0)
      acc = fmaf(bf2f(zxh[(size_t)(base + by - 3 + j)*NZX + DINNER + c]), cw[c*4+j], acc);
  }
  float v = acc / (1.f + expf(-acc));
  xconv[(size_t)by*CONVDIM + c] = f2bf(v);
}

// ---- dt = softplus(dtraw + bias); la = dt * A ----
__global__ __launch_bounds__(256) void dt_f32(const float* __restrict__ dtraw, long base,
    const float* __restrict__ dtb, const float* __restrict__ alog,
    float* __restrict__ dtv, float* __restrict__ lav){
  int i = blockIdx.x*256 + threadIdx.x;
  int lr = i >> 5, h = i & 31;
  float xv = dtraw[(size_t)(base + lr)*128 + h] + dtb[h];
  float sp = (xv > 20.f) ? xv : log1pf(expf(xv));
  float A = -expf(alog[h]);
  dtv[i] = sp;
  lav[i] = sp * A;
}

// ---- scan phase 1: per (chunk,head) decay prefix + G = X^T.Bw; grid (NC, NHEADS) ----
__global__ __launch_bounds__(256) void scan_pre(const ushort* __restrict__ xcv,
    const float* __restrict__ dtv, const float* __restrict__ lav,
    ushort* __restrict__ gbuf, float* __restrict__ lgbuf){
  const int c = blockIdx.x, h = blockIdx.y;
  const int tid = threadIdx.x, lane = tid & 63, w = tid >> 6;
  const int l15 = lane & 15, quad = lane >> 4, kq = quad*8;
  __shared__ float wsx[Q];
  __shared__ __align__(16) ushort XT[64*72];    // [p][s]
  __shared__ __align__(16) ushort BTw[128*72];  // [n][s], weighted
  const int c0 = c*Q;
  if (tid < 64){
    float la = lav[(size_t)(c0+tid)*NHEADS + h];
    float dt = dtv[(size_t)(c0+tid)*NHEADS + h];
    float v = la;
    #pragma unroll
    for (int off=1; off<64; off<<=1){ float u = __shfl_up(v, off); if (tid >= off) v += u; }
    float tot = __shfl(v, 63);
    wsx[tid] = __expf(tot - v)*dt;
    lgbuf[((size_t)h*NC + c)*Q + tid] = v;
  }
  __syncthreads();
  { int s = tid>>2, pb = (tid&3)*16;
    const ushort* src = xcv + (size_t)(c0+s)*CONVDIM + h*64 + pb;
    ushort tmp[16];
    *(uint4*)tmp     = *(const uint4*)src;
    *(uint4*)(tmp+8) = *(const uint4*)(src+8);
    #pragma unroll
    for (int i=0;i<16;i++) XT[(pb+i)*72 + s] = tmp[i];
  }
  { int s = tid>>2, nb4 = (tid&3)*32;
    const ushort* src = xcv + (size_t)(c0+s)*CONVDIM + DINNER + nb4;
    float wv = wsx[s];
    ushort tmp[32];
    #pragma unroll
    for (int v4=0;v4<4;v4++) *(uint4*)(tmp+v4*8) = *(const uint4*)(src+v4*8);
    #pragma unroll
    for (int i=0;i<32;i++) BTw[(nb4+i)*72 + s] = f2bf(bf2f(tmp[i])*wv);
  }
  __syncthreads();
  f32x4 g[8] = {};
  #pragma unroll
  for (int kb=0;kb<2;kb++){
    bf16x8 afr = *(const bf16x8*)(XT + (16*w + l15)*72 + kb*32 + kq);
    #pragma unroll
    for (int j=0;j<8;j++){
      bf16x8 bfr = *(const bf16x8*)(BTw + (16*j + l15)*72 + kb*32 + kq);
      g[j] = __builtin_amdgcn_mfma_f32_16x16x32_bf16(afr, bfr, g[j], 0,0,0);
    }
  }
  ushort* gdst = gbuf + ((size_t)h*NC + c)*8192;   // [p][n] row-major
  #pragma unroll
  for (int j=0;j<8;j++)
    #pragma unroll
    for (int r=0;r<4;r++)
      gdst[(16*w + quad*4 + r)*128 + 16*j + l15] = f2bf(g[j][r]);
}

// ---- scan phase 2: sequential carry over NC chunks; grid (NHEADS) ----
__global__ __launch_bounds__(256) void scan_carry(const ushort* __restrict__ gbuf,
    const float* __restrict__ lgbuf, ushort* __restrict__ hinit,
    float* __restrict__ hstate, int b, int init){
  const int h = blockIdx.x;
  const int tid = threadIdx.x;
  float hreg[32];
  float* hst = hstate + ((size_t)b*NHEADS + h)*8192 + (size_t)tid*32;
  if (init){
    #pragma unroll
    for (int i=0;i<32;i++) hreg[i] = 0.f;
  } else {
    #pragma unroll
    for (int k=0;k<8;k++){
      float4 v = *(const float4*)(hst + k*4);
      hreg[k*4]=v.x; hreg[k*4+1]=v.y; hreg[k*4+2]=v.z; hreg[k*4+3]=v.w;
    }
  }
  for (int c=0;c<NC;c++){
    const size_t base = ((size_t)h*NC + c)*8192 + (size_t)tid*32;
    ushort* hw = hinit + base;
    #pragma unroll
    for (int k=0;k<4;k++){
      ushort u[8];
      #pragma unroll
      for (int i=0;i<8;i++) u[i] = f2bf(hreg[k*8+i]);
      *(uint4*)(hw + k*8) = *(uint4*)u;
    }
    float e = __expf(lgbuf[((size_t)h*NC + c)*Q + 63]);
    const ushort* gr = gbuf + base;
    #pragma unroll
    for (int k=0;k<4;k++){
      uint4 gu = *(const uint4*)(gr + k*8);
      const ushort* gus = (const ushort*)&gu;
      #pragma unroll
      for (int i=0;i<8;i++) hreg[k*8+i] = fmaf(hreg[k*8+i], e, bf2f(gus[i]));
    }
  }
  #pragma unroll
  for (int k=0;k<8;k++)
    *(float4*)(hst + k*4) = make_float4(hreg[k*4],hreg[k*4+1],hreg[k*4+2],hreg[k*4+3]);
}

// ---- scan phase 3: y = els*(C.h_init) + P.X + Dp*x; grid (NC, NHEADS) ----
__global__ __launch_bounds__(256) void scan_y(const ushort* __restrict__ xcv,
    const float* __restrict__ dtv, const float* __restrict__ lgbuf,
    const ushort* __restrict__ hinit, const float* __restrict__ Dp,
    ushort* __restrict__ yb){
  const int c = blockIdx.x, h = blockIdx.y;
  const int tid = threadIdx.x, lane = tid & 63, w = tid >> 6;
  const int l15 = lane & 15, quad = lane >> 4, kq = quad*8;
  __shared__ float lg[Q], dts[Q], els[Q];
  __shared__ __align__(16) ushort XT[64*72];    // [p][s]
  __shared__ __align__(16) ushort Ps[64*72];    // [t][s]
  const int c0 = c*Q;
  if (tid < 64){
    float v = lgbuf[((size_t)h*NC + c)*Q + tid];
    lg[tid] = v;
    els[tid] = __expf(v);
    dts[tid] = dtv[(size_t)(c0+tid)*NHEADS + h];
  }
  { int s = tid>>2, pb = (tid&3)*16;
    const ushort* src = xcv + (size_t)(c0+s)*CONVDIM + h*64 + pb;
    ushort tmp[16];
    *(uint4*)tmp     = *(const uint4*)src;
    *(uint4*)(tmp+8) = *(const uint4*)(src+8);
    #pragma unroll
    for (int i=0;i<16;i++) XT[(pb+i)*72 + s] = tmp[i];
  }
  __syncthreads();
  {
    const ushort* Crow = xcv + (size_t)(c0 + 16*w + l15)*CONVDIM + DINNER + DSTATE;
    f32x4 sac[4] = {};
    #pragma unroll
    for (int kb=0;kb<4;kb++){
      bf16x8 afr = *(const bf16x8*)(Crow + kb*32 + kq);
      #pragma unroll
      for (int j=0;j<4;j++){
        const ushort* Brow = xcv + (size_t)(c0 + 16*j + l15)*CONVDIM + DINNER;
        bf16x8 bfr = *(const bf16x8*)(Brow + kb*32 + kq);
        sac[j] = __builtin_amdgcn_mfma_f32_16x16x32_bf16(afr, bfr, sac[j], 0,0,0);
      }
    }
    #pragma unroll
    for (int j=0;j<4;j++){
      int s = 16*j + l15;
      float lgs = lg[s], dtss = dts[s];
      #pragma unroll
      for (int r=0;r<4;r++){
        int t = 16*w + quad*4 + r;
        float val = (t >= s) ? sac[j][r]*__expf(lg[t]-lgs)*dtss : 0.f;
        Ps[t*72 + s] = f2bf(val);
      }
    }
  }
  __syncthreads();
  {
    const float dph = Dp[h];
    bf16x8 hb[4], xb[2];
    const ushort* hrow = hinit + ((size_t)h*NC + c)*8192 + (16*w + l15)*128;
    #pragma unroll
    for (int kb=0;kb<4;kb++) hb[kb] = *(const bf16x8*)(hrow + kb*32 + kq);
    #pragma unroll
    for (int kb=0;kb<2;kb++) xb[kb] = *(const bf16x8*)(XT + (16*w + l15)*72 + kb*32 + kq);
    #pragma unroll
    for (int i=0;i<4;i++){
      const ushort* Crow = xcv + (size_t)(c0 + 16*i + l15)*CONVDIM + DINNER + DSTATE;
      f32x4 y2 = {};
      #pragma unroll
      for (int kb=0;kb<4;kb++){
        bf16x8 afr = *(const bf16x8*)(Crow + kb*32 + kq);
        y2 = __builtin_amdgcn_mfma_f32_16x16x32_bf16(afr, hb[kb], y2, 0,0,0);
      }
      f32x4 y1 = {};
      #pragma unroll
      for (int kb=0;kb<2;kb++){
        bf16x8 afr = *(const bf16x8*)(Ps + (16*i + l15)*72 + kb*32 + kq);
        y1 = __builtin_amdgcn_mfma_f32_16x16x32_bf16(afr, xb[kb], y1, 0,0,0);
      }
      int p = 16*w + l15;
      #pragma unroll
      for (int r=0;r<4;r++){
        int t = 16*i + quad*4 + r;
        float xv = bf2f(XT[p*72 + t]);
        float yv = y1[r] + els[t]*y2[r] + dph*xv;
        yb[(size_t)(c0 + t)*DINNER + h*64 + p] = f2bf(yv);
      }
    }
  }
}

// ---- y(bf16) *= silu(z from bf16 zxbh); RMSNorm(2048) * norm_w -> out (bf16) ----
__global__ __launch_bounds__(256) void gate_norm(const ushort* __restrict__ yb,
    const ushort* __restrict__ zrow0, ushort* __restrict__ out, int ostride,
    const float* __restrict__ nw){
  int lr = blockIdx.x, tid = threadIdx.x;
  int d0 = tid*8;
  const ushort* yrow = yb + (size_t)lr*DINNER;
  const ushort* zrow = zrow0 + (size_t)lr*NZX;
  float y[8]; float ss = 0.f;
  #pragma unroll
  for (int i=0;i<8;i++){
    float z = bf2f(zrow[d0+i]);
    float g = z / (1.f + expf(-z));
    float v = bf2f(yrow[d0+i]) * g;
    y[i] = v; ss += v*v;
  }
  #pragma unroll
  for (int m=1;m<64;m<<=1) ss += __shfl_xor(ss, m);
  __shared__ float red[4];
  if ((tid & 63) == 0) red[tid>>6] = ss;
  __syncthreads();
  ss = red[0]+red[1]+red[2]+red[3];
  float scale = rsqrtf(ss * (1.f/DINNER) + 1e-5f);
  ushort* orow = out + (size_t)lr*ostride;
  #pragma unroll
  for (int i=0;i<8;i++)
    orow[d0+i] = f2bf(y[i] * scale * nw[d0+i]);
}

extern "C" void kernel_launch(void* const* d_in, const int* in_sizes, int n_in,
                              void* d_out, int out_size, void* d_ws, size_t ws_size,
                              hipStream_t stream) {
  const float* x    = (const float*)d_in[0];
  const float* ipw  = (const float*)d_in[1];
  const float* cw   = (const float*)d_in[2];
  const float* cb   = (const float*)d_in[3];
  const float* dtb  = (const float*)d_in[4];
  const float* alog = (const float*)d_in[5];
  const float* Dp   = (const float*)d_in[6];
  const float* nw   = (const float*)d_in[7];
  const float* opw  = (const float*)d_in[8];
  char* ws = (char*)d_ws;
  size_t off = 0;
  ushort* xbf    = (ushort*)(ws + off); off += (size_t)ROWS*DMODEL*2;      // 16.8 MB
  ushort* Wp     = (ushort*)(ws + off); off += (size_t)4480*DMODEL*2;      //  9.2 MB
  ushort* opwb   = (ushort*)(ws + off); off += (size_t)DMODEL*DINNER*2;    //  4.2 MB
  float*  dtv    = (float*)(ws + off);  off += (size_t)ROWS*NHEADS*4;      //  1.05 MB
  float*  lav    = (float*)(ws + off);  off += (size_t)ROWS*NHEADS*4;      //  1.05 MB
  ushort* yb     = (ushort*)(ws + off); off += (size_t)CL*DINNER*2;        //  4.2 MB
  ushort* gbuf   = (ushort*)(ws + off); off += (size_t)NHEADS*NC*8192*2;   //  8.4 MB
  ushort* hinit  = (ushort*)(ws + off); off += (size_t)NHEADS*NC*8192*2;   //  8.4 MB
  float*  lgbuf  = (float*)(ws + off);  off += (size_t)NHEADS*NC*Q*4;      //  0.13 MB
  float*  hstate = (float*)(ws + off);  off += (size_t)2*NHEADS*8192*4;    //  2.1 MB
  // fixed ~55.4 MB

  const size_t zb_big = (size_t)ROWS*NZX*2;        // 71.3 MB
  const size_t db_big = (size_t)ROWS*128*4;        //  4.2 MB
  const size_t xc_big = (size_t)ROWS*CONVDIM*2;    // 37.7 MB
  const size_t xc_sm  = (size_t)CL*CONVDIM*2;      //  4.7 MB
  const size_t zb_sm  = (size_t)1152*NZX*2;        // 10.0 MB
  const size_t db_sm  = (size_t)1152*128*4;        //  0.6 MB
  const size_t ygsz   = (size_t)ROWS*DINNER*2;     // 33.6 MB

  int mode;
  if      (ws_size >= off + zb_big + db_big + xc_big) mode = 2;   // ~169 MB
  else if (ws_size >= off + zb_big + db_big + xc_sm)  mode = 1;   // ~136 MB
  else                                                mode = 0;   // ~104 MB

  ushort* zxbh; float* dtraw; ushort* xconv; ushort* yg = nullptr;
  if (mode >= 1){
    zxbh  = (ushort*)(ws + off); off += zb_big;
    dtraw = (float*)(ws + off);  off += db_big;
    xconv = (ushort*)(ws + off); off += (mode == 2) ? xc_big : xc_sm;
  } else {
    zxbh  = (ushort*)(ws + off); off += zb_sm;
    dtraw = (float*)(ws + off);  off += db_sm;
    xconv = (ushort*)(ws + off); off += xc_sm;
    yg    = (ushort*)(ws + off); off += ygsz;
  }

  cvt_k<<<ROWS*DMODEL/8/256, 256, 0, stream>>>((const float4*)x, (uint4*)xbf);
  padw_cvt<<<4480, 256, 0, stream>>>((const float4*)ipw, (ushort4*)Wp);
  cvt_k<<<DMODEL*DINNER/8/256, 256, 0, stream>>>((const float4*)opw, (uint4*)opwb);

  if (mode >= 1){
    // ---- one merged gemm1: M=8192, N=4352, bf16 out ----
    { int nwg = 34*64;
      gemm_tile<<<dim3(34, 64), 256, 0, stream>>>(
          xbf, DMODEL, 0, (long)ROWS-1, Wp, DMODEL,
          zxbh, NZX, DMODEL, 1, 1, nwg/8, nwg%8); }
    // ---- dt columns, f32 out (W rows 4352..4479; cols >=4384 are zero-pad) ----
    gemm_tile<<<dim3(1, 64), 256, 0, stream>>>(
        xbf, DMODEL, 0, (long)ROWS-1, Wp + (size_t)NZX*DMODEL, DMODEL,
        dtraw, 128, DMODEL, 0, 0, 0, 0);
    if (mode == 2){
      conv_act<<<dim3(CONVDIM/256, ROWS), 256, 0, stream>>>(zxbh, cw, cb, xconv, 0, 0L);
      dt_f32<<<ROWS*NHEADS/256, 256, 0, stream>>>(dtraw, 0L, dtb, alog, dtv, lav);
    }
    for (int ck = 0; ck < 8; ck++){
      int b  = ck >> 2;
      int l0 = (ck & 3) * CL;            // within-sequence offset
      long g0 = (long)b*LL + l0;         // global row
      if (mode == 1){
        conv_act<<<dim3(CONVDIM/256, CL), 256, 0, stream>>>(zxbh, cw, cb, xconv, l0, g0);
        dt_f32<<<CL*NHEADS/256, 256, 0, stream>>>(dtraw, g0, dtb, alog, dtv, lav);
      }
      const ushort* xcv = xconv + ((mode == 2) ? (size_t)ck*CL*CONVDIM : 0);
      const float*  dvp = dtv   + ((mode == 2) ? (size_t)ck*CL*NHEADS  : 0);
      const float*  lvp = lav   + ((mode == 2) ? (size_t)ck*CL*NHEADS  : 0);
      scan_pre<<<dim3(NC, NHEADS), 256, 0, stream>>>(xcv, dvp, lvp, gbuf, lgbuf);
      scan_carry<<<NHEADS, 256, 0, stream>>>(gbuf, lgbuf, hinit, hstate, b, (l0==0)?1:0);
      scan_y<<<dim3(NC, NHEADS), 256, 0, stream>>>(xcv, dvp, lgbuf, hinit, Dp, yb);
      // in-place: yg row g -> zxbh[g][2048..4095] (xBC cols already consumed)
      gate_norm<<<CL, 256, 0, stream>>>(yb, zxbh + (size_t)g0*NZX,
                                        zxbh + (size_t)g0*NZX + DINNER, NZX, nw);
    }
    // ---- batched gemm2 from in-place yg ----
    { int nwg = 8*64;
      gemm_tile<<<dim3(8, 64), 256, 0, stream>>>(
          zxbh + DINNER, NZX, 0, (long)ROWS-1, opwb, DINNER,
          (float*)d_out, DMODEL, DINNER, 0, 1, nwg/8, nwg%8); }
  } else {
    // ---- fallback: per-chunk gemm1 ----
    for (int ck = 0; ck < 8; ck++){
      int b  = ck >> 2;
      int l0 = (ck & 3) * CL;
      long g0 = (long)b*LL + l0;
      long grow0 = g0 - 3;
      { int nwg = 34*9;
        gemm_tile<<<dim3(34, 9), 256, 0, stream>>>(
            xbf, DMODEL, grow0, (long)ROWS-1, Wp, DMODEL,
            zxbh, NZX, DMODEL, 1, 1, nwg/8, nwg%8); }
      gemm_tile<<<dim3(1, 9), 256, 0, stream>>>(
          xbf, DMODEL, grow0, (long)ROWS-1, Wp + (size_t)NZX*DMODEL, DMODEL,
          dtraw, 128, DMODEL, 0, 0, 0, 0);
      conv_act<<<dim3(CONVDIM/256, CL), 256, 0, stream>>>(zxbh, cw, cb, xconv, l0, 3L);
      dt_f32<<<CL*NHEADS/256, 256, 0, stream>>>(dtraw, 3L, dtb, alog, dtv, lav);
      scan_pre<<<dim3(NC, NHEADS), 256, 0, stream>>>(xconv, dtv, lav, gbuf, lgbuf);
      scan_carry<<<NHEADS, 256, 0, stream>>>(gbuf, lgbuf, hinit, hstate, b, (l0==0)?1:0);
      scan_y<<<dim3(NC, NHEADS), 256, 0, stream>>>(xconv, dtv, lgbuf, hinit, Dp, yb);
      gate_norm<<<CL, 256, 0, stream>>>(yb, zxbh + (size_t)3*NZX,
                                        yg + (size_t)ck*CL*DINNER, DINNER, nw);
    }
    { int nwg = 8*64;
      gemm_tile<<<dim3(8, 64), 256, 0, stream>>>(
          yg, DINNER, 0, (long)ROWS-1, opwb, DINNER,
          (float*)d_out, DMODEL, DINNER, 0, 1, nwg/8, nwg%8); }
  }
}

// Round 4
// 530.920 us; speedup vs baseline: 2.3708x; 1.4259x over previous
//
#include <hip/hip_runtime.h>

#define LL 4096
#define DMODEL 1024
#define DINNER 2048
#define NHEADS 32
#define DSTATE 128
#define DINPROJ 4384
#define NZX 4352           // zxbh bf16 row stride (z 2048 + xBC 2304)
#define CONVDIM 2304
#define ROWS 8192
#define Q 64               // scan sub-chunk
#define NCS 64             // chunks per sequence (LL/Q)

typedef __attribute__((ext_vector_type(8))) __bf16 bf16x8;
typedef __attribute__((ext_vector_type(4))) float f32x4;

__device__ __forceinline__ float bf2f(ushort u){ union{uint i;float f;} v; v.i=(uint)u<<16; return v.f; }
__device__ __forceinline__ ushort f2bf(float f){ union{float f;uint i;} v; v.f=f; uint r=v.i+0x7fffu+((v.i>>16)&1u); return (ushort)(r>>16); }

// ---- f32 -> bf16, 8 elems/thread ----
__global__ __launch_bounds__(256) void cvt_k(const float4* __restrict__ src, uint4* __restrict__ dst){
  long t = (long)blockIdx.x*256 + threadIdx.x;
  float4 a = src[t*2], b = src[t*2+1];
  ushort u[8] = { f2bf(a.x),f2bf(a.y),f2bf(a.z),f2bf(a.w),
                  f2bf(b.x),f2bf(b.y),f2bf(b.z),f2bf(b.w) };
  dst[t] = *(uint4*)u;
}

// ---- in_proj_w f32 (4384x1024) -> padded bf16 (4480x1024) ----
__global__ __launch_bounds__(256) void padw_cvt(const float4* __restrict__ W, ushort4* __restrict__ Wp){
  int row = blockIdx.x, c = threadIdx.x;
  ushort4 o = make_ushort4(0,0,0,0);
  if (row < DINPROJ){
    float4 f = W[(size_t)row*256 + c];
    o = make_ushort4(f2bf(f.x), f2bf(f.y), f2bf(f.z), f2bf(f.w));
  }
  Wp[(size_t)row*256 + c] = o;
}

// ---- async global->LDS, 16B per lane ----
__device__ __forceinline__ void gld16(const void* g, void* l){
  __builtin_amdgcn_global_load_lds((const __attribute__((address_space(1))) void*)g,
                                   (__attribute__((address_space(3))) void*)l, 16, 0, 0);
}

#define GBM 128
#define GBN 128
#define GBK 32

// ---- bf16 MFMA GEMM: C[m,n] = A[clamp(grow0+m)][:K] . W[n][:K] ----
// 128x128, BK=32, dbuf gld_lds (linear dest), XOR swizzle both sides.
// n-blocks with n0 >= NZX write f32 to Cdt (dt columns, ldc 128).
// swz: bijective XCD chunking; rectangular m-band x n-sweep when divisible.
__global__ __launch_bounds__(256) void gemm_tile(
    const ushort* __restrict__ A, int lda, long grow0, long rowmax,
    const ushort* __restrict__ W, int ldw,
    void* __restrict__ Cv, int ldc, int K, int obf, int swz, int q, int r,
    float* __restrict__ Cdt){
  __shared__ __align__(16) ushort As[2][GBM*GBK];
  __shared__ __align__(16) ushort Bs[2][GBN*GBK];
  const int tid = threadIdx.x;
  const int lane = tid & 63, wave = tid >> 6;
  const int wm = wave >> 1, wn = wave & 1;
  int bx, by;
  if (swz){
    int wgid = blockIdx.y * gridDim.x + blockIdx.x;
    int xcd = wgid & 7, i = wgid >> 3;
    int vid = (xcd < r) ? xcd*(q+1) + i : r*(q+1) + (xcd - r)*q + i;
    int rows = gridDim.y;
    if (((rows & 7) == 0) && (r == 0)){
      int rp = rows >> 3;
      int lv = vid - xcd*q;
      by = xcd*rp + (lv % rp);      // XCD owns contiguous m-band
      bx = lv / rp;                 // sweep n within band (A-band L2-resident)
    } else { by = vid / (int)gridDim.x; bx = vid % (int)gridDim.x; }
  } else { bx = blockIdx.x; by = blockIdx.y; }
  const int m0 = by * GBM, n0 = bx * GBN;

  const int srow = lane >> 2;
  const int scol = (((lane & 3) ^ ((lane >> 3) & 3)) * 8);
  long ra0 = grow0 + m0 + 16*wave + srow;      if (ra0 < 0) ra0 = 0; if (ra0 > rowmax) ra0 = rowmax;
  long ra1 = grow0 + m0 + 64 + 16*wave + srow; if (ra1 < 0) ra1 = 0; if (ra1 > rowmax) ra1 = rowmax;
  const ushort* gA0 = A + ra0*(long)lda + scol;
  const ushort* gA1 = A + ra1*(long)lda + scol;
  const ushort* gB0 = W + (size_t)(n0 + 16*wave + srow)*ldw + scol;
  const ushort* gB1 = W + (size_t)(n0 + 64 + 16*wave + srow)*ldw + scol;
  ushort* lA0 = &As[0][0] + (16*wave)*GBK;
  ushort* lA1 = &As[0][0] + (64 + 16*wave)*GBK;
  ushort* lB0 = &Bs[0][0] + (16*wave)*GBK;
  ushort* lB1 = &Bs[0][0] + (64 + 16*wave)*GBK;

  const int fr = lane & 15, quad = lane >> 4;
  const int es = ((quad ^ ((fr >> 1) & 3)) * 8);
  f32x4 acc[4][4] = {};

#define STAGE(buf, ko) { \
    gld16(gA0 + (ko), lA0 + (buf)*(GBM*GBK)); \
    gld16(gA1 + (ko), lA1 + (buf)*(GBM*GBK)); \
    gld16(gB0 + (ko), lB0 + (buf)*(GBN*GBK)); \
    gld16(gB1 + (ko), lB1 + (buf)*(GBN*GBK)); }

  STAGE(0, 0);
  __syncthreads();
  int cur = 0;
  const int nst = K / GBK;
  for (int s = 0; s < nst; ++s){
    if (s + 1 < nst) STAGE(cur^1, (s+1)*GBK);
    const ushort* Ab = &As[cur][0];
    const ushort* Bb = &Bs[cur][0];
    bf16x8 af[4], bw[4];
    #pragma unroll
    for (int i=0;i<4;i++) af[i] = *(const bf16x8*)(Ab + (wm*64 + i*16 + fr)*GBK + es);
    #pragma unroll
    for (int j=0;j<4;j++) bw[j] = *(const bf16x8*)(Bb + (wn*64 + j*16 + fr)*GBK + es);
    #pragma unroll
    for (int i=0;i<4;i++)
      #pragma unroll
      for (int j=0;j<4;j++)
        acc[i][j] = __builtin_amdgcn_mfma_f32_16x16x32_bf16(af[i], bw[j], acc[i][j], 0,0,0);
    if (s + 1 < nst){ __syncthreads(); cur ^= 1; }
  }
#undef STAGE
  if (Cdt && n0 >= NZX){
    int nb = n0 - NZX;
    #pragma unroll
    for (int i=0;i<4;i++)
      #pragma unroll
      for (int j=0;j<4;j++){
        size_t base = (size_t)(m0 + wm*64 + i*16 + quad*4)*128 + (nb + wn*64 + j*16 + fr);
        #pragma unroll
        for (int rr=0;rr<4;rr++)
          Cdt[base + (size_t)rr*128] = acc[i][j][rr];
      }
  } else if (obf){
    ushort* Cb = (ushort*)Cv;
    #pragma unroll
    for (int i=0;i<4;i++)
      #pragma unroll
      for (int j=0;j<4;j++){
        size_t base = (size_t)(m0 + wm*64 + i*16 + quad*4)*ldc + (n0 + wn*64 + j*16 + fr);
        #pragma unroll
        for (int rr=0;rr<4;rr++)
          Cb[base + (size_t)rr*ldc] = f2bf(acc[i][j][rr]);
      }
  } else {
    float* Cf = (float*)Cv;
    #pragma unroll
    for (int i=0;i<4;i++)
      #pragma unroll
      for (int j=0;j<4;j++){
        size_t base = (size_t)(m0 + wm*64 + i*16 + quad*4)*ldc + (n0 + wn*64 + j*16 + fr);
        #pragma unroll
        for (int rr=0;rr<4;rr++)
          Cf[base + (size_t)rr*ldc] = acc[i][j][rr];
      }
  }
}

// ---- depthwise conv4 + bias + SiLU from bf16 zxbh; bf16 out (buffer-local rows) ----
__global__ __launch_bounds__(256) void conv_act(const ushort* __restrict__ zxh,
    const float* __restrict__ cw, const float* __restrict__ cb,
    ushort* __restrict__ xconv, int l0, long base){
  int c = blockIdx.x*256 + threadIdx.x;             // 0..2303
  int by = blockIdx.y;
  int l = (l0 + by) & (LL-1);
  float acc = cb[c];
  #pragma unroll
  for (int j=0;j<4;j++){
    if (l - 3 + j >= 0)
      acc = fmaf(bf2f(zxh[(size_t)(base + by - 3 + j)*NZX + DINNER + c]), cw[c*4+j], acc);
  }
  float v = acc / (1.f + expf(-acc));
  xconv[(size_t)by*CONVDIM + c] = f2bf(v);
}

// ---- scan phase 1: decay prefix (inline softplus) + G = X^T.Bw ----
// grid (nchunks, NHEADS); xcv rows buffer-local; dtraw rows global (dtrow0+).
__global__ __launch_bounds__(256) void scan_pre2(const ushort* __restrict__ xcv,
    const float* __restrict__ dtraw, long dtrow0,
    const float* __restrict__ dtb, const float* __restrict__ alog,
    ushort* __restrict__ gbuf, float* __restrict__ lgbuf, int cslot0){
  const int c = blockIdx.x, h = blockIdx.y;
  const int cslot = cslot0 + c;
  const int tid = threadIdx.x, lane = tid & 63, w = tid >> 6;
  const int l15 = lane & 15, quad = lane >> 4, kq = quad*8;
  __shared__ float wsx[Q];
  __shared__ __align__(16) ushort XT[64*72];    // [p][s]
  __shared__ __align__(16) ushort BTw[128*72];  // [n][s], weighted
  const int c0 = c*Q;
  if (tid < 64){
    float xv = dtraw[(size_t)(dtrow0 + c0 + tid)*128 + h] + dtb[h];
    float sp = (xv > 20.f) ? xv : log1pf(expf(xv));
    float la = sp * (-expf(alog[h]));
    float v = la;
    #pragma unroll
    for (int off=1; off<64; off<<=1){ float u = __shfl_up(v, off); if (tid >= off) v += u; }
    float tot = __shfl(v, 63);
    wsx[tid] = __expf(tot - v)*sp;
    lgbuf[((size_t)h*NCS + cslot)*Q + tid] = v;
  }
  __syncthreads();
  { int s = tid>>2, pb = (tid&3)*16;
    const ushort* src = xcv + (size_t)(c0+s)*CONVDIM + h*64 + pb;
    ushort tmp[16];
    *(uint4*)tmp     = *(const uint4*)src;
    *(uint4*)(tmp+8) = *(const uint4*)(src+8);
    #pragma unroll
    for (int i=0;i<16;i++) XT[(pb+i)*72 + s] = tmp[i];
  }
  { int s = tid>>2, nb4 = (tid&3)*32;
    const ushort* src = xcv + (size_t)(c0+s)*CONVDIM + DINNER + nb4;
    float wv = wsx[s];
    ushort tmp[32];
    #pragma unroll
    for (int v4=0;v4<4;v4++) *(uint4*)(tmp+v4*8) = *(const uint4*)(src+v4*8);
    #pragma unroll
    for (int i=0;i<32;i++) BTw[(nb4+i)*72 + s] = f2bf(bf2f(tmp[i])*wv);
  }
  __syncthreads();
  f32x4 g[8] = {};
  #pragma unroll
  for (int kb=0;kb<2;kb++){
    bf16x8 afr = *(const bf16x8*)(XT + (16*w + l15)*72 + kb*32 + kq);
    #pragma unroll
    for (int j=0;j<8;j++){
      bf16x8 bfr = *(const bf16x8*)(BTw + (16*j + l15)*72 + kb*32 + kq);
      g[j] = __builtin_amdgcn_mfma_f32_16x16x32_bf16(afr, bfr, g[j], 0,0,0);
    }
  }
  ushort* gdst = gbuf + ((size_t)h*NCS + cslot)*8192;   // [p][n] row-major
  #pragma unroll
  for (int j=0;j<8;j++)
    #pragma unroll
    for (int r=0;r<4;r++)
      gdst[(16*w + quad*4 + r)*128 + 16*j + l15] = f2bf(g[j][r]);
}

// ---- scan phase 2: sequential carry over ncs chunks, IN-PLACE over gbuf ----
// grid (4, NHEADS): each block owns a 2048-elem quarter of the 8192 state.
// Depth-2 register prefetch of g (state-independent loads).
__global__ __launch_bounds__(256) void scan_carry2(ushort* __restrict__ gh,
    const float* __restrict__ lgbuf, int ncs){
  const int qtr = blockIdx.x, h = blockIdx.y;
  const int tid = threadIdx.x;
  __shared__ float es[NCS];
  if (tid < ncs) es[tid] = __expf(lgbuf[((size_t)h*NCS + tid)*Q + 63]);
  __syncthreads();
  float hreg[8] = {0.f,0.f,0.f,0.f,0.f,0.f,0.f,0.f};
  ushort* p0 = gh + (size_t)h*NCS*8192 + qtr*2048 + tid*8;
  uint4 g0 = *(const uint4*)p0;
  uint4 g1 = *(const uint4*)(p0 + 8192);
  for (int c = 0; c < ncs; ++c){
    ushort* pc = p0 + (size_t)c*8192;
    uint4 gc = g0; g0 = g1;
    if (c + 2 < ncs) g1 = *(const uint4*)(pc + 2*8192);
    ushort u[8];
    #pragma unroll
    for (int i=0;i<8;i++) u[i] = f2bf(hreg[i]);
    *(uint4*)pc = *(uint4*)u;                     // h_init(c) overwrites g(c)
    float e = es[c];
    const ushort* gs = (const ushort*)&gc;
    #pragma unroll
    for (int i=0;i<8;i++) hreg[i] = fmaf(hreg[i], e, bf2f(gs[i]));
  }
}

// ---- scan phase 3: y = els*(C.h_init) + P.X + Dp*x; y IN-PLACE into xcv x-cols ----
__global__ __launch_bounds__(256) void scan_y2(ushort* __restrict__ xcv,
    const float* __restrict__ dtraw, long dtrow0,
    const float* __restrict__ dtb, const float* __restrict__ alog,
    const float* __restrict__ lgbuf, const ushort* __restrict__ gbuf,
    const float* __restrict__ Dp, int cslot0){
  const int c = blockIdx.x, h = blockIdx.y;
  const int cslot = cslot0 + c;
  const int tid = threadIdx.x, lane = tid & 63, w = tid >> 6;
  const int l15 = lane & 15, quad = lane >> 4, kq = quad*8;
  __shared__ float lg[Q], dts[Q], els[Q];
  __shared__ __align__(16) ushort XT[64*72];    // [p][s]
  __shared__ __align__(16) ushort Ps[64*72];    // [t][s]
  const int c0 = c*Q;
  if (tid < 64){
    float v = lgbuf[((size_t)h*NCS + cslot)*Q + tid];
    lg[tid] = v;
    els[tid] = __expf(v);
    float xv = dtraw[(size_t)(dtrow0 + c0 + tid)*128 + h] + dtb[h];
    dts[tid] = (xv > 20.f) ? xv : log1pf(expf(xv));
  }
  { int s = tid>>2, pb = (tid&3)*16;
    const ushort* src = xcv + (size_t)(c0+s)*CONVDIM + h*64 + pb;
    ushort tmp[16];
    *(uint4*)tmp     = *(const uint4*)src;
    *(uint4*)(tmp+8) = *(const uint4*)(src+8);
    #pragma unroll
    for (int i=0;i<16;i++) XT[(pb+i)*72 + s] = tmp[i];
  }
  __syncthreads();
  {
    const ushort* Crow = xcv + (size_t)(c0 + 16*w + l15)*CONVDIM + DINNER + DSTATE;
    f32x4 sac[4] = {};
    #pragma unroll
    for (int kb=0;kb<4;kb++){
      bf16x8 afr = *(const bf16x8*)(Crow + kb*32 + kq);
      #pragma unroll
      for (int j=0;j<4;j++){
        const ushort* Brow = xcv + (size_t)(c0 + 16*j + l15)*CONVDIM + DINNER;
        bf16x8 bfr = *(const bf16x8*)(Brow + kb*32 + kq);
        sac[j] = __builtin_amdgcn_mfma_f32_16x16x32_bf16(afr, bfr, sac[j], 0,0,0);
      }
    }
    #pragma unroll
    for (int j=0;j<4;j++){
      int s = 16*j + l15;
      float lgs = lg[s], dtss = dts[s];
      #pragma unroll
      for (int r=0;r<4;r++){
        int t = 16*w + quad*4 + r;
        float val = (t >= s) ? sac[j][r]*__expf(lg[t]-lgs)*dtss : 0.f;
        Ps[t*72 + s] = f2bf(val);
      }
    }
  }
  __syncthreads();
  {
    const float dph = Dp[h];
    bf16x8 hb[4], xb[2];
    const ushort* hrow = gbuf + ((size_t)h*NCS + cslot)*8192 + (16*w + l15)*128;
    #pragma unroll
    for (int kb=0;kb<4;kb++) hb[kb] = *(const bf16x8*)(hrow + kb*32 + kq);
    #pragma unroll
    for (int kb=0;kb<2;kb++) xb[kb] = *(const bf16x8*)(XT + (16*w + l15)*72 + kb*32 + kq);
    #pragma unroll
    for (int i=0;i<4;i++){
      const ushort* Crow = xcv + (size_t)(c0 + 16*i + l15)*CONVDIM + DINNER + DSTATE;
      f32x4 y2 = {};
      #pragma unroll
      for (int kb=0;kb<4;kb++){
        bf16x8 afr = *(const bf16x8*)(Crow + kb*32 + kq);
        y2 = __builtin_amdgcn_mfma_f32_16x16x32_bf16(afr, hb[kb], y2, 0,0,0);
      }
      f32x4 y1 = {};
      #pragma unroll
      for (int kb=0;kb<2;kb++){
        bf16x8 afr = *(const bf16x8*)(Ps + (16*i + l15)*72 + kb*32 + kq);
        y1 = __builtin_amdgcn_mfma_f32_16x16x32_bf16(afr, xb[kb], y1, 0,0,0);
      }
      int p = 16*w + l15;
      #pragma unroll
      for (int r=0;r<4;r++){
        int t = 16*i + quad*4 + r;
        float xv = bf2f(XT[p*72 + t]);
        float yv = y1[r] + els[t]*y2[r] + dph*xv;
        xcv[(size_t)(c0 + t)*CONVDIM + h*64 + p] = f2bf(yv);   // in-place y
      }
    }
  }
}

// ---- y(in xconv x-cols) *= silu(z); RMSNorm * nw -> zxbh x-region (bf16) ----
__global__ __launch_bounds__(256) void gate_norm2(const ushort* __restrict__ ybase,
    const ushort* __restrict__ zbase, ushort* __restrict__ obase,
    const float* __restrict__ nw){
  int lr = blockIdx.x, tid = threadIdx.x;
  int d0 = tid*8;
  const ushort* yrow = ybase + (size_t)lr*CONVDIM;
  const ushort* zrow = zbase + (size_t)lr*NZX;
  float y[8]; float ss = 0.f;
  #pragma unroll
  for (int i=0;i<8;i++){
    float z = bf2f(zrow[d0+i]);
    float g = z / (1.f + expf(-z));
    float v = bf2f(yrow[d0+i]) * g;
    y[i] = v; ss += v*v;
  }
  #pragma unroll
  for (int m=1;m<64;m<<=1) ss += __shfl_xor(ss, m);
  __shared__ float red[4];
  if ((tid & 63) == 0) red[tid>>6] = ss;
  __syncthreads();
  ss = red[0]+red[1]+red[2]+red[3];
  float scale = rsqrtf(ss * (1.f/DINNER) + 1e-5f);
  ushort* orow = obase + (size_t)lr*NZX;
  #pragma unroll
  for (int i=0;i<8;i++)
    orow[d0+i] = f2bf(y[i] * scale * nw[d0+i]);
}

extern "C" void kernel_launch(void* const* d_in, const int* in_sizes, int n_in,
                              void* d_out, int out_size, void* d_ws, size_t ws_size,
                              hipStream_t stream) {
  const float* x    = (const float*)d_in[0];
  const float* ipw  = (const float*)d_in[1];
  const float* cw   = (const float*)d_in[2];
  const float* cb   = (const float*)d_in[3];
  const float* dtb  = (const float*)d_in[4];
  const float* alog = (const float*)d_in[5];
  const float* Dp   = (const float*)d_in[6];
  const float* nw   = (const float*)d_in[7];
  const float* opw  = (const float*)d_in[8];
  char* ws = (char*)d_ws;
  size_t off = 0;
  ushort* Wp    = (ushort*)(ws + off); off += (size_t)4480*DMODEL*2;     //  9.18 MB
  ushort* opwb  = (ushort*)(ws + off); off += (size_t)DMODEL*DINNER*2;   //  4.19 MB
  float*  lgbuf = (float*)(ws + off);  off += (size_t)NHEADS*NCS*Q*4;    //  0.52 MB
  float*  dtraw = (float*)(ws + off);  off += (size_t)ROWS*128*4;        //  4.19 MB
  ushort* zxbh  = (ushort*)(ws + off); off += (size_t)ROWS*NZX*2;        // 71.30 MB
  size_t off_xc = off;

  const size_t xc_fast = (size_t)LL*CONVDIM*2;      // 18.87 MB (per-seq)
  const size_t xc_fb   = (size_t)1024*CONVDIM*2;    //  4.72 MB (per-chunk)
  const size_t gb_sz   = (size_t)NHEADS*NCS*8192*2; // 33.55 MB
  const size_t xbf_sz  = (size_t)ROWS*DMODEL*2;     // 16.78 MB (overlaid by gbuf)

  size_t need_fast = off + xc_fast + gb_sz;         // ~141.8 MB
  int fast = (ws_size >= need_fast) ? 1 : 0;

  ushort* xconv = (ushort*)(ws + off_xc);
  size_t off_tail = off_xc + (fast ? xc_fast : xc_fb);
  ushort* xbf  = (ushort*)(ws + off_tail);          // dead after gemm1
  ushort* gbuf = (ushort*)(ws + off_tail);          // overlays xbf

  cvt_k<<<ROWS*DMODEL/8/256, 256, 0, stream>>>((const float4*)x, (uint4*)xbf);
  padw_cvt<<<4480, 256, 0, stream>>>((const float4*)ipw, (ushort4*)Wp);
  cvt_k<<<DMODEL*DINNER/8/256, 256, 0, stream>>>((const float4*)opw, (uint4*)opwb);

  // merged in_proj GEMM incl dt columns: grid (35,64), nwg=2240 (q=280,r=0)
  gemm_tile<<<dim3(35, 64), 256, 0, stream>>>(
      xbf, DMODEL, 0, (long)ROWS-1, Wp, DMODEL,
      zxbh, NZX, DMODEL, 1, 1, 280, 0, dtraw);

  for (int b = 0; b < 2; ++b){
    long row0 = (long)b*LL;
    if (fast){
      conv_act<<<dim3(CONVDIM/256, LL), 256, 0, stream>>>(zxbh, cw, cb, xconv, 0, row0);
      scan_pre2<<<dim3(NCS, NHEADS), 256, 0, stream>>>(
          xconv, dtraw, row0, dtb, alog, gbuf, lgbuf, 0);
      scan_carry2<<<dim3(4, NHEADS), 256, 0, stream>>>(gbuf, lgbuf, NCS);
      scan_y2<<<dim3(NCS, NHEADS), 256, 0, stream>>>(
          xconv, dtraw, row0, dtb, alog, lgbuf, gbuf, Dp, 0);
      gate_norm2<<<LL, 256, 0, stream>>>(
          xconv, zxbh + (size_t)row0*NZX, zxbh + (size_t)row0*NZX + DINNER, nw);
    } else {
      for (int ckl = 0; ckl < 4; ++ckl){
        long g0 = row0 + (long)ckl*1024;
        conv_act<<<dim3(CONVDIM/256, 1024), 256, 0, stream>>>(zxbh, cw, cb, xconv, ckl*1024, g0);
        scan_pre2<<<dim3(16, NHEADS), 256, 0, stream>>>(
            xconv, dtraw, g0, dtb, alog, gbuf, lgbuf, ckl*16);
      }
      scan_carry2<<<dim3(4, NHEADS), 256, 0, stream>>>(gbuf, lgbuf, NCS);
      for (int ckl = 0; ckl < 4; ++ckl){
        long g0 = row0 + (long)ckl*1024;
        conv_act<<<dim3(CONVDIM/256, 1024), 256, 0, stream>>>(zxbh, cw, cb, xconv, ckl*1024, g0);
        scan_y2<<<dim3(16, NHEADS), 256, 0, stream>>>(
            xconv, dtraw, g0, dtb, alog, lgbuf, gbuf, Dp, ckl*16);
        gate_norm2<<<1024, 256, 0, stream>>>(
            xconv, zxbh + (size_t)g0*NZX, zxbh + (size_t)g0*NZX + DINNER, nw);
      }
    }
  }

  // out-proj GEMM: A = normed y (in zxbh x-region), grid (8,64), nwg=512 (q=64,r=0)
  gemm_tile<<<dim3(8, 64), 256, 0, stream>>>(
      zxbh + DINNER, NZX, 0, (long)ROWS-1, opwb, DINNER,
      (float*)d_out, DMODEL, DINNER, 0, 1, 64, 0, nullptr);
}

// Round 6
// 492.610 us; speedup vs baseline: 2.5551x; 1.0778x over previous
//
#include <hip/hip_runtime.h>

#define LL 4096
#define DMODEL 1024
#define DINNER 2048
#define NHEADS 32
#define DSTATE 128
#define DINPROJ 4384
#define NZX 4352           // zxbh bf16 row stride (z 2048 + xBC 2304)
#define CONVDIM 2304
#define ROWS 8192
#define Q 64               // scan sub-chunk
#define NCS 64             // chunks per sequence (LL/Q)

typedef __attribute__((ext_vector_type(8))) __bf16 bf16x8;
typedef __attribute__((ext_vector_type(4))) float f32x4;

__device__ __forceinline__ float bf2f(ushort u){ union{uint i;float f;} v; v.i=(uint)u<<16; return v.f; }
__device__ __forceinline__ ushort f2bf(float f){ union{float f;uint i;} v; v.f=f; uint r=v.i+0x7fffu+((v.i>>16)&1u); return (ushort)(r>>16); }

// ---- f32 -> bf16, 8 elems/thread ----
__global__ __launch_bounds__(256) void cvt_k(const float4* __restrict__ src, uint4* __restrict__ dst){
  long t = (long)blockIdx.x*256 + threadIdx.x;
  float4 a = src[t*2], b = src[t*2+1];
  ushort u[8] = { f2bf(a.x),f2bf(a.y),f2bf(a.z),f2bf(a.w),
                  f2bf(b.x),f2bf(b.y),f2bf(b.z),f2bf(b.w) };
  dst[t] = *(uint4*)u;
}

// ---- in_proj_w f32 (4384x1024) -> padded bf16 (4480x1024) ----
__global__ __launch_bounds__(256) void padw_cvt(const float4* __restrict__ W, ushort4* __restrict__ Wp){
  int row = blockIdx.x, c = threadIdx.x;
  ushort4 o = make_ushort4(0,0,0,0);
  if (row < DINPROJ){
    float4 f = W[(size_t)row*256 + c];
    o = make_ushort4(f2bf(f.x), f2bf(f.y), f2bf(f.z), f2bf(f.w));
  }
  Wp[(size_t)row*256 + c] = o;
}

// ---- async global->LDS, 16B per lane ----
__device__ __forceinline__ void gld16(const void* g, void* l){
  __builtin_amdgcn_global_load_lds((const __attribute__((address_space(1))) void*)g,
                                   (__attribute__((address_space(3))) void*)l, 16, 0, 0);
}

#define GBM 128
#define GBN 128
#define GBK 32

// ---- bf16 MFMA GEMM: C[m,n] = A[clamp(grow0+m)][:K] . W[n][:K] ----
__global__ __launch_bounds__(256) void gemm_tile(
    const ushort* __restrict__ A, int lda, long grow0, long rowmax,
    const ushort* __restrict__ W, int ldw,
    void* __restrict__ Cv, int ldc, int K, int obf, int swz, int q, int r,
    float* __restrict__ Cdt){
  __shared__ __align__(16) ushort As[2][GBM*GBK];
  __shared__ __align__(16) ushort Bs[2][GBN*GBK];
  const int tid = threadIdx.x;
  const int lane = tid & 63, wave = tid >> 6;
  const int wm = wave >> 1, wn = wave & 1;
  int bx, by;
  if (swz){
    int wgid = blockIdx.y * gridDim.x + blockIdx.x;
    int xcd = wgid & 7, i = wgid >> 3;
    int vid = (xcd < r) ? xcd*(q+1) + i : r*(q+1) + (xcd - r)*q + i;
    int rows = gridDim.y;
    if (((rows & 7) == 0) && (r == 0)){
      int rp = rows >> 3;
      int lv = vid - xcd*q;
      by = xcd*rp + (lv % rp);      // XCD owns contiguous m-band
      bx = lv / rp;                 // sweep n within band (A-band L2-resident)
    } else { by = vid / (int)gridDim.x; bx = vid % (int)gridDim.x; }
  } else { bx = blockIdx.x; by = blockIdx.y; }
  const int m0 = by * GBM, n0 = bx * GBN;

  const int srow = lane >> 2;
  const int scol = (((lane & 3) ^ ((lane >> 3) & 3)) * 8);
  long ra0 = grow0 + m0 + 16*wave + srow;      if (ra0 < 0) ra0 = 0; if (ra0 > rowmax) ra0 = rowmax;
  long ra1 = grow0 + m0 + 64 + 16*wave + srow; if (ra1 < 0) ra1 = 0; if (ra1 > rowmax) ra1 = rowmax;
  const ushort* gA0 = A + ra0*(long)lda + scol;
  const ushort* gA1 = A + ra1*(long)lda + scol;
  const ushort* gB0 = W + (size_t)(n0 + 16*wave + srow)*ldw + scol;
  const ushort* gB1 = W + (size_t)(n0 + 64 + 16*wave + srow)*ldw + scol;
  ushort* lA0 = &As[0][0] + (16*wave)*GBK;
  ushort* lA1 = &As[0][0] + (64 + 16*wave)*GBK;
  ushort* lB0 = &Bs[0][0] + (16*wave)*GBK;
  ushort* lB1 = &Bs[0][0] + (64 + 16*wave)*GBK;

  const int fr = lane & 15, quad = lane >> 4;
  const int es = ((quad ^ ((fr >> 1) & 3)) * 8);
  f32x4 acc[4][4] = {};

#define STAGE(buf, ko) { \
    gld16(gA0 + (ko), lA0 + (buf)*(GBM*GBK)); \
    gld16(gA1 + (ko), lA1 + (buf)*(GBM*GBK)); \
    gld16(gB0 + (ko), lB0 + (buf)*(GBN*GBK)); \
    gld16(gB1 + (ko), lB1 + (buf)*(GBN*GBK)); }

  STAGE(0, 0);
  __syncthreads();
  int cur = 0;
  const int nst = K / GBK;
  for (int s = 0; s < nst; ++s){
    if (s + 1 < nst) STAGE(cur^1, (s+1)*GBK);
    const ushort* Ab = &As[cur][0];
    const ushort* Bb = &Bs[cur][0];
    bf16x8 af[4], bw[4];
    #pragma unroll
    for (int i=0;i<4;i++) af[i] = *(const bf16x8*)(Ab + (wm*64 + i*16 + fr)*GBK + es);
    #pragma unroll
    for (int j=0;j<4;j++) bw[j] = *(const bf16x8*)(Bb + (wn*64 + j*16 + fr)*GBK + es);
    #pragma unroll
    for (int i=0;i<4;i++)
      #pragma unroll
      for (int j=0;j<4;j++)
        acc[i][j] = __builtin_amdgcn_mfma_f32_16x16x32_bf16(af[i], bw[j], acc[i][j], 0,0,0);
    if (s + 1 < nst){ __syncthreads(); cur ^= 1; }
  }
#undef STAGE
  if (Cdt && n0 >= NZX){
    int nb = n0 - NZX;
    #pragma unroll
    for (int i=0;i<4;i++)
      #pragma unroll
      for (int j=0;j<4;j++){
        size_t base = (size_t)(m0 + wm*64 + i*16 + quad*4)*128 + (nb + wn*64 + j*16 + fr);
        #pragma unroll
        for (int rr=0;rr<4;rr++)
          Cdt[base + (size_t)rr*128] = acc[i][j][rr];
      }
  } else if (obf){
    ushort* Cb = (ushort*)Cv;
    #pragma unroll
    for (int i=0;i<4;i++)
      #pragma unroll
      for (int j=0;j<4;j++){
        size_t base = (size_t)(m0 + wm*64 + i*16 + quad*4)*ldc + (n0 + wn*64 + j*16 + fr);
        #pragma unroll
        for (int rr=0;rr<4;rr++)
          Cb[base + (size_t)rr*ldc] = f2bf(acc[i][j][rr]);
      }
  } else {
    float* Cf = (float*)Cv;
    #pragma unroll
    for (int i=0;i<4;i++)
      #pragma unroll
      for (int j=0;j<4;j++){
        size_t base = (size_t)(m0 + wm*64 + i*16 + quad*4)*ldc + (n0 + wn*64 + j*16 + fr);
        #pragma unroll
        for (int rr=0;rr<4;rr++)
          Cf[base + (size_t)rr*ldc] = acc[i][j][rr];
      }
  }
}

// ---- depthwise conv4 + bias + SiLU; 4 rows x 8 ch per thread, sliding window ----
__global__ __launch_bounds__(256) void conv8(const ushort* __restrict__ zxh,
    const float* __restrict__ cw, const float* __restrict__ cb,
    ushort* __restrict__ xconv, int l0, long base){
  int id = blockIdx.x*256 + threadIdx.x;
  int g = id % 288, band = id / 288;
  int c = g*8;
  float w[8][4], bias[8];
  #pragma unroll
  for (int i=0;i<8;i++){
    bias[i] = cb[c+i];
    #pragma unroll
    for (int j=0;j<4;j++) w[i][j] = cw[(c+i)*4+j];
  }
  float in[7][8];
  #pragma unroll
  for (int k=0;k<7;k++){
    int lrow = l0 + band*4 - 3 + k;
    if (lrow < 0){
      #pragma unroll
      for (int i=0;i<8;i++) in[k][i] = 0.f;
    } else {
      uint4 v = *(const uint4*)(zxh + (size_t)(base + band*4 - 3 + k)*NZX + DINNER + c);
      const ushort* us = (const ushort*)&v;
      #pragma unroll
      for (int i=0;i<8;i++) in[k][i] = bf2f(us[i]);
    }
  }
  #pragma unroll
  for (int r=0;r<4;r++){
    ushort o[8];
    #pragma unroll
    for (int i=0;i<8;i++){
      float a = bias[i];
      #pragma unroll
      for (int j=0;j<4;j++) a = fmaf(in[r+j][i], w[i][j], a);
      float v = a / (1.f + expf(-a));
      o[i] = f2bf(v);
    }
    *(uint4*)(xconv + (size_t)(band*4 + r)*CONVDIM + c) = *(uint4*)o;
  }
}

// ---- scan phase 1: decay prefix (inline softplus) + G = X^T.Bw ----
__global__ __launch_bounds__(256) void scan_pre2(const ushort* __restrict__ xcv,
    const float* __restrict__ dtraw, long dtrow0,
    const float* __restrict__ dtb, const float* __restrict__ alog,
    ushort* __restrict__ gbuf, float* __restrict__ lgbuf, int cslot0){
  const int c = blockIdx.x, h = blockIdx.y;
  const int cslot = cslot0 + c;
  const int tid = threadIdx.x, lane = tid & 63, w = tid >> 6;
  const int l15 = lane & 15, quad = lane >> 4, kq = quad*8;
  __shared__ float wsx[Q];
  __shared__ __align__(16) ushort XT[64*72];    // [p][s]
  __shared__ __align__(16) ushort BTw[128*72];  // [n][s], weighted; reused as g-stage
  const int c0 = c*Q;
  if (tid < 64){
    float xv = dtraw[(size_t)(dtrow0 + c0 + tid)*128 + h] + dtb[h];
    float sp = (xv > 20.f) ? xv : log1pf(expf(xv));
    float la = sp * (-expf(alog[h]));
    float v = la;
    #pragma unroll
    for (int off=1; off<64; off<<=1){ float u = __shfl_up(v, off); if (tid >= off) v += u; }
    float tot = __shfl(v, 63);
    wsx[tid] = __expf(tot - v)*sp;
    lgbuf[((size_t)h*NCS + cslot)*Q + tid] = v;
  }
  __syncthreads();
  { int s = tid>>2, pb = (tid&3)*16;
    const ushort* src = xcv + (size_t)(c0+s)*CONVDIM + h*64 + pb;
    ushort tmp[16];
    *(uint4*)tmp     = *(const uint4*)src;
    *(uint4*)(tmp+8) = *(const uint4*)(src+8);
    #pragma unroll
    for (int i=0;i<16;i++) XT[(pb+i)*72 + s] = tmp[i];
  }
  { int s = tid>>2, nb4 = (tid&3)*32;
    const ushort* src = xcv + (size_t)(c0+s)*CONVDIM + DINNER + nb4;
    float wv = wsx[s];
    ushort tmp[32];
    #pragma unroll
    for (int v4=0;v4<4;v4++) *(uint4*)(tmp+v4*8) = *(const uint4*)(src+v4*8);
    #pragma unroll
    for (int i=0;i<32;i++) BTw[(nb4+i)*72 + s] = f2bf(bf2f(tmp[i])*wv);
  }
  __syncthreads();
  f32x4 g[8] = {};
  #pragma unroll
  for (int kb=0;kb<2;kb++){
    bf16x8 afr = *(const bf16x8*)(XT + (16*w + l15)*72 + kb*32 + kq);
    #pragma unroll
    for (int j=0;j<8;j++){
      bf16x8 bfr = *(const bf16x8*)(BTw + (16*j + l15)*72 + kb*32 + kq);
      g[j] = __builtin_amdgcn_mfma_f32_16x16x32_bf16(afr, bfr, g[j], 0,0,0);
    }
  }
  // stage g into LDS (reuse BTw; stride 136 ushorts = 272B, 16B-aligned rows)
  __syncthreads();
  ushort* gst = &BTw[0];                 // [p][136] staging, 64*136 = 8704 <= 9216
  #pragma unroll
  for (int j=0;j<8;j++)
    #pragma unroll
    for (int r=0;r<4;r++)
      gst[(16*w + quad*4 + r)*136 + 16*j + l15] = f2bf(g[j][r]);
  __syncthreads();
  // drain: 64 rows x 128 cols = 8192 ushorts; 256 threads x 32 each
  { int row = tid >> 2, seg = tid & 3;
    const ushort* gs = gst + row*136 + seg*32;
    uint4 a = *(const uint4*)(gs);
    uint4 b = *(const uint4*)(gs + 8);
    uint4 c2 = *(const uint4*)(gs + 16);
    uint4 d = *(const uint4*)(gs + 24);
    ushort* gdst = gbuf + ((size_t)h*NCS + cslot)*8192 + row*128 + seg*32;
    *(uint4*)gdst = a;
    *(uint4*)(gdst + 8) = b;
    *(uint4*)(gdst + 16) = c2;
    *(uint4*)(gdst + 24) = d;
  }
}

// ---- scan phase 2: sequential carry, IN-PLACE over gbuf; depth-2 prefetch ----
__global__ __launch_bounds__(256) void scan_carry2(ushort* __restrict__ gh,
    const float* __restrict__ lgbuf, int ncs){
  const int qtr = blockIdx.x, h = blockIdx.y;
  const int tid = threadIdx.x;
  __shared__ float es[NCS];
  if (tid < ncs) es[tid] = __expf(lgbuf[((size_t)h*NCS + tid)*Q + 63]);
  __syncthreads();
  float hreg[8] = {0.f,0.f,0.f,0.f,0.f,0.f,0.f,0.f};
  ushort* p0 = gh + (size_t)h*NCS*8192 + qtr*2048 + tid*8;
  uint4 g0 = *(const uint4*)p0;
  uint4 g1 = *(const uint4*)(p0 + 8192);
  for (int c = 0; c < ncs; ++c){
    ushort* pc = p0 + (size_t)c*8192;
    uint4 gc = g0; g0 = g1;
    if (c + 2 < ncs) g1 = *(const uint4*)(pc + 2*8192);
    ushort u[8];
    #pragma unroll
    for (int i=0;i<8;i++) u[i] = f2bf(hreg[i]);
    *(uint4*)pc = *(uint4*)u;                     // h_init(c) overwrites g(c)
    float e = es[c];
    const ushort* gs = (const ushort*)&gc;
    #pragma unroll
    for (int i=0;i<8;i++) hreg[i] = fmaf(hreg[i], e, bf2f(gs[i]));
  }
}

// ---- scan phase 3: y = els*(C.h_init) + P.X + Dp*x; y staged in LDS, coalesced ----
__global__ __launch_bounds__(256) void scan_y2(ushort* __restrict__ xcv,
    const float* __restrict__ dtraw, long dtrow0,
    const float* __restrict__ dtb, const float* __restrict__ alog,
    const float* __restrict__ lgbuf, const ushort* __restrict__ gbuf,
    const float* __restrict__ Dp, int cslot0){
  const int c = blockIdx.x, h = blockIdx.y;
  const int cslot = cslot0 + c;
  const int tid = threadIdx.x, lane = tid & 63, w = tid >> 6;
  const int l15 = lane & 15, quad = lane >> 4, kq = quad*8;
  __shared__ float lg[Q], dts[Q], els[Q];
  __shared__ __align__(16) ushort XT[64*72];    // [p][s]
  __shared__ __align__(16) ushort Ps[64*72];    // [t][s]; reused as y-stage [t][72]
  const int c0 = c*Q;
  if (tid < 64){
    float v = lgbuf[((size_t)h*NCS + cslot)*Q + tid];
    lg[tid] = v;
    els[tid] = __expf(v);
    float xv = dtraw[(size_t)(dtrow0 + c0 + tid)*128 + h] + dtb[h];
    dts[tid] = (xv > 20.f) ? xv : log1pf(expf(xv));
  }
  { int s = tid>>2, pb = (tid&3)*16;
    const ushort* src = xcv + (size_t)(c0+s)*CONVDIM + h*64 + pb;
    ushort tmp[16];
    *(uint4*)tmp     = *(const uint4*)src;
    *(uint4*)(tmp+8) = *(const uint4*)(src+8);
    #pragma unroll
    for (int i=0;i<16;i++) XT[(pb+i)*72 + s] = tmp[i];
  }
  __syncthreads();
  {
    const ushort* Crow = xcv + (size_t)(c0 + 16*w + l15)*CONVDIM + DINNER + DSTATE;
    f32x4 sac[4] = {};
    #pragma unroll
    for (int kb=0;kb<4;kb++){
      bf16x8 afr = *(const bf16x8*)(Crow + kb*32 + kq);
      #pragma unroll
      for (int j=0;j<4;j++){
        const ushort* Brow = xcv + (size_t)(c0 + 16*j + l15)*CONVDIM + DINNER;
        bf16x8 bfr = *(const bf16x8*)(Brow + kb*32 + kq);
        sac[j] = __builtin_amdgcn_mfma_f32_16x16x32_bf16(afr, bfr, sac[j], 0,0,0);
      }
    }
    #pragma unroll
    for (int j=0;j<4;j++){
      int s = 16*j + l15;
      float lgs = lg[s], dtss = dts[s];
      #pragma unroll
      for (int r=0;r<4;r++){
        int t = 16*w + quad*4 + r;
        float val = (t >= s) ? sac[j][r]*__expf(lg[t]-lgs)*dtss : 0.f;
        Ps[t*72 + s] = f2bf(val);
      }
    }
  }
  __syncthreads();
  float yv[4][4];
  {
    const float dph = Dp[h];
    bf16x8 hb[4], xb[2];
    const ushort* hrow = gbuf + ((size_t)h*NCS + cslot)*8192 + (16*w + l15)*128;
    #pragma unroll
    for (int kb=0;kb<4;kb++) hb[kb] = *(const bf16x8*)(hrow + kb*32 + kq);
    #pragma unroll
    for (int kb=0;kb<2;kb++) xb[kb] = *(const bf16x8*)(XT + (16*w + l15)*72 + kb*32 + kq);
    #pragma unroll
    for (int i=0;i<4;i++){
      const ushort* Crow = xcv + (size_t)(c0 + 16*i + l15)*CONVDIM + DINNER + DSTATE;
      f32x4 y2 = {};
      #pragma unroll
      for (int kb=0;kb<4;kb++){
        bf16x8 afr = *(const bf16x8*)(Crow + kb*32 + kq);
        y2 = __builtin_amdgcn_mfma_f32_16x16x32_bf16(afr, hb[kb], y2, 0,0,0);
      }
      f32x4 y1 = {};
      #pragma unroll
      for (int kb=0;kb<2;kb++){
        bf16x8 afr = *(const bf16x8*)(Ps + (16*i + l15)*72 + kb*32 + kq);
        y1 = __builtin_amdgcn_mfma_f32_16x16x32_bf16(afr, xb[kb], y1, 0,0,0);
      }
      int p = 16*w + l15;
      #pragma unroll
      for (int r=0;r<4;r++){
        int t = 16*i + quad*4 + r;
        float xv = bf2f(XT[p*72 + t]);
        yv[i][r] = y1[r] + els[t]*y2[r] + dph*xv;
      }
    }
  }
  // stage y into LDS (reuse Ps), then coalesced 16B stores
  __syncthreads();
  {
    int p = 16*w + l15;
    #pragma unroll
    for (int i=0;i<4;i++)
      #pragma unroll
      for (int r=0;r<4;r++)
        Ps[(16*i + quad*4 + r)*72 + p] = f2bf(yv[i][r]);
  }
  __syncthreads();
  { int t = tid >> 2, seg = tid & 3;
    uint4 a = *(const uint4*)(Ps + t*72 + seg*16);
    uint4 b = *(const uint4*)(Ps + t*72 + seg*16 + 8);
    ushort* od = xcv + (size_t)(c0 + t)*CONVDIM + h*64 + seg*16;
    *(uint4*)od = a;
    *(uint4*)(od + 8) = b;
  }
}

// ---- y(in xconv x-cols) *= silu(z); RMSNorm * nw -> zxbh x-region (bf16) ----
__global__ __launch_bounds__(256) void gate_norm2(const ushort* __restrict__ ybase,
    const ushort* __restrict__ zbase, ushort* __restrict__ obase,
    const float* __restrict__ nw){
  int lr = blockIdx.x, tid = threadIdx.x;
  int d0 = tid*8;
  const ushort* yrow = ybase + (size_t)lr*CONVDIM;
  const ushort* zrow = zbase + (size_t)lr*NZX;
  uint4 yu = *(const uint4*)(yrow + d0);
  uint4 zu = *(const uint4*)(zrow + d0);
  const ushort* yus = (const ushort*)&yu;
  const ushort* zus = (const ushort*)&zu;
  float y[8]; float ss = 0.f;
  #pragma unroll
  for (int i=0;i<8;i++){
    float z = bf2f(zus[i]);
    float g = z / (1.f + expf(-z));
    float v = bf2f(yus[i]) * g;
    y[i] = v; ss += v*v;
  }
  #pragma unroll
  for (int m=1;m<64;m<<=1) ss += __shfl_xor(ss, m);
  __shared__ float red[4];
  if ((tid & 63) == 0) red[tid>>6] = ss;
  __syncthreads();
  ss = red[0]+red[1]+red[2]+red[3];
  float scale = rsqrtf(ss * (1.f/DINNER) + 1e-5f);
  ushort o[8];
  #pragma unroll
  for (int i=0;i<8;i++)
    o[i] = f2bf(y[i] * scale * nw[d0+i]);
  *(uint4*)(obase + (size_t)lr*NZX + d0) = *(uint4*)o;
}

extern "C" void kernel_launch(void* const* d_in, const int* in_sizes, int n_in,
                              void* d_out, int out_size, void* d_ws, size_t ws_size,
                              hipStream_t stream) {
  const float* x    = (const float*)d_in[0];
  const float* ipw  = (const float*)d_in[1];
  const float* cw   = (const float*)d_in[2];
  const float* cb   = (const float*)d_in[3];
  const float* dtb  = (const float*)d_in[4];
  const float* alog = (const float*)d_in[5];
  const float* Dp   = (const float*)d_in[6];
  const float* nw   = (const float*)d_in[7];
  const float* opw  = (const float*)d_in[8];
  char* ws = (char*)d_ws;
  size_t off = 0;
  ushort* Wp    = (ushort*)(ws + off); off += (size_t)4480*DMODEL*2;     //  9.18 MB
  ushort* opwb  = (ushort*)(ws + off); off += (size_t)DMODEL*DINNER*2;   //  4.19 MB
  float*  lgbuf = (float*)(ws + off);  off += (size_t)NHEADS*NCS*Q*4;    //  0.52 MB
  float*  dtraw = (float*)(ws + off);  off += (size_t)ROWS*128*4;        //  4.19 MB
  ushort* zxbh  = (ushort*)(ws + off); off += (size_t)ROWS*NZX*2;        // 71.30 MB
  size_t off_xc = off;

  const size_t xc_fast = (size_t)LL*CONVDIM*2;      // 18.87 MB (per-seq)
  const size_t xc_fb   = (size_t)1024*CONVDIM*2;    //  4.72 MB (per-chunk)
  const size_t gb_sz   = (size_t)NHEADS*NCS*8192*2; // 33.55 MB

  size_t need_fast = off + xc_fast + gb_sz;         // ~141.8 MB
  int fast = (ws_size >= need_fast) ? 1 : 0;

  ushort* xconv = (ushort*)(ws + off_xc);
  size_t off_tail = off_xc + (fast ? xc_fast : xc_fb);
  ushort* xbf  = (ushort*)(ws + off_tail);          // dead after gemm1
  ushort* gbuf = (ushort*)(ws + off_tail);          // overlays xbf

  cvt_k<<<ROWS*DMODEL/8/256, 256, 0, stream>>>((const float4*)x, (uint4*)xbf);
  padw_cvt<<<4480, 256, 0, stream>>>((const float4*)ipw, (ushort4*)Wp);
  cvt_k<<<DMODEL*DINNER/8/256, 256, 0, stream>>>((const float4*)opw, (uint4*)opwb);

  // merged in_proj GEMM incl dt columns: grid (35,64), nwg=2240 (q=280,r=0)
  gemm_tile<<<dim3(35, 64), 256, 0, stream>>>(
      xbf, DMODEL, 0, (long)ROWS-1, Wp, DMODEL,
      zxbh, NZX, DMODEL, 1, 1, 280, 0, dtraw);

  for (int b = 0; b < 2; ++b){
    long row0 = (long)b*LL;
    if (fast){
      conv8<<<288*(LL/4)/256, 256, 0, stream>>>(zxbh, cw, cb, xconv, 0, row0);
      scan_pre2<<<dim3(NCS, NHEADS), 256, 0, stream>>>(
          xconv, dtraw, row0, dtb, alog, gbuf, lgbuf, 0);
      scan_carry2<<<dim3(4, NHEADS), 256, 0, stream>>>(gbuf, lgbuf, NCS);
      scan_y2<<<dim3(NCS, NHEADS), 256, 0, stream>>>(
          xconv, dtraw, row0, dtb, alog, lgbuf, gbuf, Dp, 0);
      gate_norm2<<<LL, 256, 0, stream>>>(
          xconv, zxbh + (size_t)row0*NZX, zxbh + (size_t)row0*NZX + DINNER, nw);
    } else {
      for (int ckl = 0; ckl < 4; ++ckl){
        long g0 = row0 + (long)ckl*1024;
        conv8<<<288*(1024/4)/256, 256, 0, stream>>>(zxbh, cw, cb, xconv, ckl*1024, g0);
        scan_pre2<<<dim3(16, NHEADS), 256, 0, stream>>>(
            xconv, dtraw, g0, dtb, alog, gbuf, lgbuf, ckl*16);
      }
      scan_carry2<<<dim3(4, NHEADS), 256, 0, stream>>>(gbuf, lgbuf, NCS);
      for (int ckl = 0; ckl < 4; ++ckl){
        long g0 = row0 + (long)ckl*1024;
        conv8<<<288*(1024/4)/256, 256, 0, stream>>>(zxbh, cw, cb, xconv, ckl*1024, g0);
        scan_y2<<<dim3(16, NHEADS), 256, 0, stream>>>(
            xconv, dtraw, g0, dtb, alog, lgbuf, gbuf, Dp, ckl*16);
        gate_norm2<<<1024, 256, 0, stream>>>(
            xconv, zxbh + (size_t)g0*NZX, zxbh + (size_t)g0*NZX + DINNER, nw);
      }
    }
  }

  // out-proj GEMM: A = normed y (in zxbh x-region), grid (8,64), nwg=512 (q=64,r=0)
  gemm_tile<<<dim3(8, 64), 256, 0, stream>>>(
      zxbh + DINNER, NZX, 0, (long)ROWS-1, opwb, DINNER,
      (float*)d_out, DMODEL, DINNER, 0, 1, 64, 0, nullptr);
}